// Round 1
// 1663.709 us; speedup vs baseline: 1.0773x; 1.0773x over previous
//
#include <hip/hip_runtime.h>

#define DIMS 64
#define SCAN_CHUNK 2048  // 256 threads * 8 elems
#define BSHIFT 10        // 1024 rows per bucket
#define BROWS (1 << BSHIFT)
#define NB_MAX 304       // >= ceil(300K/1024)=293
#define BCAP 65536       // fixed bucket capacity (mean ~34K + drain pads <54K)
#define SCAP 24          // staged entries per bucket; flush groups of 16 (64B)
#define SPITCH 25        // odd pitch -> bank-conflict-free across buckets
#define PA_THREADS 256
#define PA_K 4           // edges per thread per round (int4 vector loads)
#define PA_HALFROUND (PA_THREADS / 2 * PA_K)  // 512 edges per half per round
#define PA_HCHUNK 4096   // per-half chunk per block (8 rounds of 512)
#define PB_BLOCKS 128
#define PB_THREADS 512
#define SENTINEL 0xFFFFFFFFu

// nt 8B load of an int2 (edge record): keep the 80MB/layer CSR stream from
// polluting L2/L3, which should stay dedicated to the hot 77MB gather target
__device__ __forceinline__ int2 ld_nt_int2(const int2* p) {
  unsigned long long v =
      __builtin_nontemporal_load(reinterpret_cast<const unsigned long long*>(p));
  int2 r;
  r.x = (int)(unsigned)(v & 0xFFFFFFFFull);
  r.y = (int)(unsigned)(v >> 32);
  return r;
}

// ---------------------------------------------------------------------------
// E = concat(U_emb, V_emb), vectorized float4
// ---------------------------------------------------------------------------
__global__ __launch_bounds__(256) void init_e_kernel(
    const float* __restrict__ U, const float* __restrict__ V,
    float* __restrict__ E, int nU_elems, int total_elems) {
  int i = (blockIdx.x * blockDim.x + threadIdx.x) * 4;
  if (i >= total_elems) return;
  float4 v = (i < nU_elems)
      ? *reinterpret_cast<const float4*>(U + i)
      : *reinterpret_cast<const float4*>(V + (i - nU_elems));
  *reinterpret_cast<float4*>(E + i) = v;
}

// ---------------------------------------------------------------------------
// Pass A: LDS-staged multisplit of packed (row_low<<19 | col) 4B entries into
// fixed-capacity row-range buckets (base = b*BCAP).
// Flush quantum = 16 entries = one full 64B line at an aligned offset.
//
// Round batching: each thread stages PA_K=4 edges per round (int4 loads),
// cutting barrier rounds ~4x vs the 1-edge/thread version. Each block takes
// one chunk from the user half AND one from the item half of the
// half-sorted symmetric COO (threads 0..127 vs 128..255), so per-round
// per-bucket arrival stays ~5 << SCAP and staging retries are rare.
// Edge->block assignment is scheduling only; bucket contents are unchanged.
// ---------------------------------------------------------------------------
__global__ __launch_bounds__(PA_THREADS) void pass_a_kernel(
    const int* __restrict__ rows, const int* __restrict__ cols,
    unsigned* __restrict__ temp, int* __restrict__ gcur, int nnz, int nb) {
  __shared__ unsigned stage[NB_MAX * SPITCH];
  __shared__ int scnt[NB_MAX];
  for (int b = threadIdx.x; b < nb; b += PA_THREADS) scnt[b] = 0;
  __syncthreads();

  const int half = nnz >> 1;
  const int u0 = blockIdx.x * PA_HCHUNK;
  const int u1 = min(half, u0 + PA_HCHUNK);
  const int i0 = half + blockIdx.x * PA_HCHUNK;
  const int i1 = min(nnz, i0 + PA_HCHUNK);
  const int tid = threadIdx.x;

  for (int rd = 0; rd < PA_HCHUNK / PA_HALFROUND; ++rd) {
    // per-thread edge range for this round
    int base, lim;
    if (tid < PA_THREADS / 2) {
      base = u0 + rd * PA_HALFROUND + tid * PA_K;
      lim = u1;
    } else {
      base = i0 + rd * PA_HALFROUND + (tid - PA_THREADS / 2) * PA_K;
      lim = i1;
    }

    unsigned packed[PA_K];
    int bkt[PA_K];
    unsigned pend = 0;  // bitmask of entries not yet staged
    if (base + PA_K <= lim && ((base & 3) == 0)) {
      int4 r4 = *reinterpret_cast<const int4*>(rows + base);
      int4 c4 = *reinterpret_cast<const int4*>(cols + base);
      int rr[PA_K] = {r4.x, r4.y, r4.z, r4.w};
      int cc[PA_K] = {c4.x, c4.y, c4.z, c4.w};
#pragma unroll
      for (int k = 0; k < PA_K; ++k) {
        bkt[k] = rr[k] >> BSHIFT;
        packed[k] = ((unsigned)(rr[k] & (BROWS - 1)) << 19) | (unsigned)cc[k];
      }
      pend = (1u << PA_K) - 1;
    } else {
#pragma unroll
      for (int k = 0; k < PA_K; ++k) {
        int e = base + k;
        if (e < lim) {
          int r = rows[e];
          int c = cols[e];
          bkt[k] = r >> BSHIFT;
          packed[k] = ((unsigned)(r & (BROWS - 1)) << 19) | (unsigned)c;
          pend |= 1u << k;
        }
      }
    }

    for (;;) {
#pragma unroll
      for (int k = 0; k < PA_K; ++k) {
        if (pend & (1u << k)) {
          int idx = atomicAdd(&scnt[bkt[k]], 1);
          if (idx < SCAP) {
            stage[bkt[k] * SPITCH + idx] = packed[k];
            pend &= ~(1u << k);
          } else {
            atomicAdd(&scnt[bkt[k]], -1);  // undo failed claim; retry after flush
          }
        }
      }
      __syncthreads();
      // flush full 16-groups (one thread per bucket, conflict-free pitch)
      for (int bb = threadIdx.x; bb < nb; bb += PA_THREADS) {
        int cval = scnt[bb];
        if (cval >= 16) {
          int pos = atomicAdd(&gcur[bb], 16);
          unsigned v[16];
#pragma unroll
          for (int k = 0; k < 16; ++k) v[k] = stage[bb * SPITCH + k];
          uint4* dst = reinterpret_cast<uint4*>(&temp[pos]);
          dst[0] = make_uint4(v[0], v[1], v[2], v[3]);
          dst[1] = make_uint4(v[4], v[5], v[6], v[7]);
          dst[2] = make_uint4(v[8], v[9], v[10], v[11]);
          dst[3] = make_uint4(v[12], v[13], v[14], v[15]);
          for (int k = 0; k < cval - 16; ++k)
            stage[bb * SPITCH + k] = stage[bb * SPITCH + 16 + k];
          scnt[bb] = cval - 16;
        }
      }
      int pend_total = __syncthreads_count(pend ? 1 : 0);
      if (pend_total == 0) break;
    }
  }
  // final drain: pad residue to a full aligned 16-group with sentinels
  __syncthreads();
  for (int bb = threadIdx.x; bb < nb; bb += PA_THREADS) {
    int cval = scnt[bb];
    if (cval > 0) {
      int pos = atomicAdd(&gcur[bb], 16);
      for (int k = 0; k < 16; ++k)
        temp[pos + k] = (k < cval) ? stage[bb * SPITCH + k] : SENTINEL;
    }
  }
}

// ---------------------------------------------------------------------------
// Per-bucket histogram: LDS atomics + coalesced contiguous cnt stores.
// ---------------------------------------------------------------------------
__global__ __launch_bounds__(512) void hist_bucket_kernel(
    const unsigned* __restrict__ temp, const int* __restrict__ gcur,
    int* __restrict__ cnt, int n) {
  __shared__ int lcnt[BROWS];
  int b = blockIdx.x;
  int base_row = b << BSHIFT;
  int nrows = min(BROWS, n - base_row);
  for (int r = threadIdx.x; r < BROWS; r += 512) lcnt[r] = 0;
  __syncthreads();
  int start = b * BCAP, end = gcur[b];
  for (int i = start + threadIdx.x; i < end; i += 512) {
    unsigned ent = temp[i];
    if (ent != SENTINEL) atomicAdd(&lcnt[ent >> 19], 1);
  }
  __syncthreads();
  for (int r = threadIdx.x; r < nrows; r += 512)
    cnt[base_row + r] = lcnt[r];
}

// phase1: per-block chunk reduction
__global__ __launch_bounds__(256) void scan_phase1(
    const int* __restrict__ cnt, int* __restrict__ block_sums, int n) {
  __shared__ int sdata[256];
  int base = blockIdx.x * SCAN_CHUNK;
  int sum = 0;
#pragma unroll
  for (int k = 0; k < 8; ++k) {
    int idx = base + k * 256 + threadIdx.x;
    if (idx < n) sum += cnt[idx];
  }
  sdata[threadIdx.x] = sum;
  __syncthreads();
  for (int s = 128; s > 0; s >>= 1) {
    if (threadIdx.x < s) sdata[threadIdx.x] += sdata[threadIdx.x + s];
    __syncthreads();
  }
  if (threadIdx.x == 0) block_sums[blockIdx.x] = sdata[0];
}

// phase2: single 256-wide exclusive scan over block sums; writes row_ptr[n]
__global__ __launch_bounds__(256) void scan_phase2(
    int* __restrict__ block_sums, int n_blocks, int* __restrict__ row_ptr, int n) {
  __shared__ int tmp[256];
  int v = (threadIdx.x < n_blocks) ? block_sums[threadIdx.x] : 0;
  tmp[threadIdx.x] = v;
  __syncthreads();
  for (int offs = 1; offs < 256; offs <<= 1) {
    int t = (threadIdx.x >= offs) ? tmp[threadIdx.x - offs] : 0;
    __syncthreads();
    tmp[threadIdx.x] += t;
    __syncthreads();
  }
  if (threadIdx.x < n_blocks) block_sums[threadIdx.x] = tmp[threadIdx.x] - v;
  if (threadIdx.x == 0) row_ptr[n] = tmp[255];
}

// phase3: per-block chunk scan with offset, writes row_ptr
__global__ __launch_bounds__(256) void scan_phase3(
    const int* __restrict__ cnt, const int* __restrict__ block_sums,
    int* __restrict__ row_ptr, int n) {
  __shared__ int tmp[256];
  __shared__ int s_carry;
  int base = blockIdx.x * SCAN_CHUNK;
  if (threadIdx.x == 0) s_carry = block_sums[blockIdx.x];
  __syncthreads();
#pragma unroll 1
  for (int k = 0; k < 8; ++k) {
    int idx = base + k * 256 + threadIdx.x;
    int v = (idx < n) ? cnt[idx] : 0;
    tmp[threadIdx.x] = v;
    __syncthreads();
    for (int offs = 1; offs < 256; offs <<= 1) {
      int t = (threadIdx.x >= offs) ? tmp[threadIdx.x - offs] : 0;
      __syncthreads();
      tmp[threadIdx.x] += t;
      __syncthreads();
    }
    int incl = tmp[threadIdx.x];
    int carry = s_carry;
    if (idx < n) row_ptr[idx] = carry + incl - v;
    __syncthreads();
    if (threadIdx.x == 0) s_carry = carry + tmp[255];
    __syncthreads();
  }
}

// rs[i] = 1/sqrt(deg[i]); deg==0 -> 1
__global__ __launch_bounds__(256) void rs_kernel(
    const int* __restrict__ cnt, float* __restrict__ rs, int n) {
  int i = blockIdx.x * blockDim.x + threadIdx.x;
  if (i < n) {
    float d = (float)cnt[i];
    rs[i] = (d > 0.0f) ? 1.0f / sqrtf(d) : 1.0f;
  }
}

// gcur init for fixed-capacity buckets
__global__ __launch_bounds__(256) void bucket_init_kernel(
    int* __restrict__ gcur, int nb) {
  int b = blockIdx.x * blockDim.x + threadIdx.x;
  if (b < nb) gcur[b] = b * BCAP;
}

// ---------------------------------------------------------------------------
// Pass B: per bucket, scatter bucket entries to exact CSR positions.
// ---------------------------------------------------------------------------
__global__ __launch_bounds__(PB_THREADS) void pass_b_kernel(
    const unsigned* __restrict__ temp, const int* __restrict__ gcur,
    const int* __restrict__ row_ptr, const float* __restrict__ rs,
    int2* __restrict__ csr_cv, int nb, int n) {
  __shared__ int ldscur[BROWS];
  for (int b = blockIdx.x; b < nb; b += gridDim.x) {
    int base_row = b << BSHIFT;
    int nrows = min(BROWS, n - base_row);
    for (int r = threadIdx.x; r < nrows; r += PB_THREADS)
      ldscur[r] = row_ptr[base_row + r];
    __syncthreads();
    int start = b * BCAP, end = gcur[b];
    for (int i = start + threadIdx.x; i < end; i += PB_THREADS) {
      unsigned ent = temp[i];
      if (ent != SENTINEL) {
        int col = (int)(ent & 0x7FFFFu);
        int rlow = (int)(ent >> 19);
        int p = atomicAdd(&ldscur[rlow], 1);
        float val = rs[base_row + rlow] * rs[col];
        csr_cv[p] = make_int2(col, __float_as_int(val));
      }
    }
    __syncthreads();
  }
}

// ---------------------------------------------------------------------------
// SpMM: one wave per row; the wave's four 16-lane quarters each gather a
// different edge's row as float4 (4 edges x 256B = 1KB per instruction),
// unrolled 4 deep -> 16 edges / 4KB outstanding per wave. Edge records are
// nt-loaded (stream, no cache allocation). Quarters combined with two
// xor-shuffles; quarter 0 stores the 256B output row.
// ---------------------------------------------------------------------------
__global__ __launch_bounds__(256) void spmm_kernel(
    const int* __restrict__ row_ptr, const int2* __restrict__ csr_cv,
    const float4* __restrict__ cur4, float4* __restrict__ next4, int n_rows) {
  int row  = blockIdx.x * (blockDim.x >> 6) + (threadIdx.x >> 6);
  int lane = threadIdx.x & 63;
  int q    = lane >> 4;   // quarter: which edge of the group of 4
  int sub  = lane & 15;   // float4 index within the gathered row
  if (row >= n_rows) return;
  int start = row_ptr[row];
  int end   = row_ptr[row + 1];
  float4 acc = make_float4(0.0f, 0.0f, 0.0f, 0.0f);
  int e = start;
  for (; e + 16 <= end; e += 16) {
    int2 ed0 = ld_nt_int2(&csr_cv[e      + q]);
    int2 ed1 = ld_nt_int2(&csr_cv[e + 4  + q]);
    int2 ed2 = ld_nt_int2(&csr_cv[e + 8  + q]);
    int2 ed3 = ld_nt_int2(&csr_cv[e + 12 + q]);
    float4 g0 = cur4[ed0.x * 16 + sub];
    float4 g1 = cur4[ed1.x * 16 + sub];
    float4 g2 = cur4[ed2.x * 16 + sub];
    float4 g3 = cur4[ed3.x * 16 + sub];
    float v0 = __int_as_float(ed0.y), v1 = __int_as_float(ed1.y);
    float v2 = __int_as_float(ed2.y), v3 = __int_as_float(ed3.y);
    acc.x = fmaf(v0, g0.x, acc.x); acc.y = fmaf(v0, g0.y, acc.y);
    acc.z = fmaf(v0, g0.z, acc.z); acc.w = fmaf(v0, g0.w, acc.w);
    acc.x = fmaf(v1, g1.x, acc.x); acc.y = fmaf(v1, g1.y, acc.y);
    acc.z = fmaf(v1, g1.z, acc.z); acc.w = fmaf(v1, g1.w, acc.w);
    acc.x = fmaf(v2, g2.x, acc.x); acc.y = fmaf(v2, g2.y, acc.y);
    acc.z = fmaf(v2, g2.z, acc.z); acc.w = fmaf(v2, g2.w, acc.w);
    acc.x = fmaf(v3, g3.x, acc.x); acc.y = fmaf(v3, g3.y, acc.y);
    acc.z = fmaf(v3, g3.z, acc.z); acc.w = fmaf(v3, g3.w, acc.w);
  }
  for (; e + 4 <= end; e += 4) {
    int2 ed = ld_nt_int2(&csr_cv[e + q]);
    float4 g = cur4[ed.x * 16 + sub];
    float v = __int_as_float(ed.y);
    acc.x = fmaf(v, g.x, acc.x); acc.y = fmaf(v, g.y, acc.y);
    acc.z = fmaf(v, g.z, acc.z); acc.w = fmaf(v, g.w, acc.w);
  }
  if (e < end) {  // 1..3 remaining: masked quarters (inactive quarters w=0)
    int idx = min(e + q, end - 1);
    int2 ed = ld_nt_int2(&csr_cv[idx]);
    float4 g = cur4[ed.x * 16 + sub];
    float v = (e + q < end) ? __int_as_float(ed.y) : 0.0f;
    acc.x = fmaf(v, g.x, acc.x); acc.y = fmaf(v, g.y, acc.y);
    acc.z = fmaf(v, g.z, acc.z); acc.w = fmaf(v, g.w, acc.w);
  }
  // combine the four quarter partial sums
#pragma unroll
  for (int offs = 16; offs <= 32; offs <<= 1) {
    acc.x += __shfl_xor(acc.x, offs, 64);
    acc.y += __shfl_xor(acc.y, offs, 64);
    acc.z += __shfl_xor(acc.z, offs, 64);
    acc.w += __shfl_xor(acc.w, offs, 64);
  }
  if (q == 0) next4[row * 16 + sub] = acc;
}

// ---------------------------------------------------------------------------
__global__ __launch_bounds__(256) void gather_kernel(
    const int* __restrict__ u, const int* __restrict__ it,
    const float* __restrict__ cur, float* __restrict__ accU,
    float* __restrict__ accI, int batch, int nU) {
  int b    = blockIdx.x * (blockDim.x >> 6) + (threadIdx.x >> 6);
  int lane = threadIdx.x & 63;
  if (b >= batch) return;
  accU[b * DIMS + lane] += cur[u[b] * DIMS + lane];
  accI[b * DIMS + lane] += cur[(it[b] + nU) * DIMS + lane];
}

__global__ __launch_bounds__(256) void score_kernel(
    const float* __restrict__ accU, const float* __restrict__ accI,
    float* __restrict__ out, int batch) {
  int b    = blockIdx.x * (blockDim.x >> 6) + (threadIdx.x >> 6);
  int lane = threadIdx.x & 63;
  if (b >= batch) return;
  float v = accU[b * DIMS + lane] * accI[b * DIMS + lane];
  for (int offs = 32; offs > 0; offs >>= 1) v += __shfl_down(v, offs, 64);
  if (lane == 0) out[b] = v * (1.0f / 16.0f);
}

// ---------------------------------------------------------------------------
extern "C" void kernel_launch(void* const* d_in, const int* in_sizes, int n_in,
                              void* d_out, int out_size, void* d_ws, size_t ws_size,
                              hipStream_t stream) {
  const int*   u     = (const int*)d_in[0];
  const int*   it    = (const int*)d_in[1];
  const int*   arows = (const int*)d_in[2];
  const int*   acols = (const int*)d_in[3];
  const float* U     = (const float*)d_in[5];
  const float* V     = (const float*)d_in[6];

  const int batch = in_sizes[0];
  const int nnz   = in_sizes[2];
  const int nU    = in_sizes[5] / DIMS;
  const int nV    = in_sizes[6] / DIMS;
  const int N     = nU + nV;
  const int n_scan_blocks = (N + SCAN_CHUNK - 1) / SCAN_CHUNK;
  const int NB    = (N + BROWS - 1) >> BSHIFT;  // 293
  const size_t ebytes = (size_t)N * DIMS * 4;
  const size_t tbytes = (size_t)NB * BCAP * 4;
  const size_t xbytes = tbytes > ebytes ? tbytes : ebytes;

  // pass_a grid: each block covers one PA_HCHUNK chunk of EACH half
  const int big_half = nnz - nnz / 2;
  const int PA_B = (big_half + PA_HCHUNK - 1) / PA_HCHUNK;

  char*  ws  = (char*)d_ws;
  size_t off = 0;
  auto take = [&](size_t bytes) -> void* {
    void* p = ws + off;
    off = (off + bytes + 255) & ~(size_t)255;
    return p;
  };
  int*     cnt        = (int*)take((size_t)N * 4);
  float*   rs         = (float*)take((size_t)N * 4);
  int*     row_ptr    = (int*)take((size_t)(N + 1) * 4);
  int*     block_sums = (int*)take((size_t)256 * 4);
  int*     gcur       = (int*)take((size_t)NB * 4);
  int2*    csr_cv     = (int2*)take((size_t)nnz * 8);
  char*    X          = (char*)take(xbytes);   // temp (build), then bufA (E)
  float*   bufB       = (float*)take(ebytes);
  float*   accU       = (float*)take((size_t)batch * DIMS * 4);
  float*   accI       = (float*)take((size_t)batch * DIMS * 4);
  unsigned* temp      = (unsigned*)X;
  float*   bufA       = (float*)X;

  hipMemsetAsync(accU, 0, (size_t)batch * DIMS * 4, stream);
  hipMemsetAsync(accI, 0, (size_t)batch * DIMS * 4, stream);

  // ---- CSR build (uses X as temp) ----
  bucket_init_kernel<<<(NB + 255) / 256, 256, 0, stream>>>(gcur, NB);
  pass_a_kernel<<<PA_B, PA_THREADS, 0, stream>>>(arows, acols, temp, gcur, nnz, NB);
  hist_bucket_kernel<<<NB, 512, 0, stream>>>(temp, gcur, cnt, N);
  scan_phase1<<<n_scan_blocks, 256, 0, stream>>>(cnt, block_sums, N);
  scan_phase2<<<1, 256, 0, stream>>>(block_sums, n_scan_blocks, row_ptr, N);
  scan_phase3<<<n_scan_blocks, 256, 0, stream>>>(cnt, block_sums, row_ptr, N);
  rs_kernel<<<(N + 255) / 256, 256, 0, stream>>>(cnt, rs, N);
  pass_b_kernel<<<PB_BLOCKS, PB_THREADS, 0, stream>>>(temp, gcur, row_ptr, rs,
                                                      csr_cv, NB, N);

  // ---- E0 init (X becomes bufA now that temp is dead) ----
  {
    int total = N * DIMS;
    int t4 = total / 4;
    init_e_kernel<<<(t4 + 255) / 256, 256, 0, stream>>>(U, V, bufA, nU * DIMS, total);
  }
  gather_kernel<<<(batch + 3) / 4, 256, 0, stream>>>(u, it, bufA, accU, accI, batch, nU);

  float* cur = bufA;
  float* nxt = bufB;
  for (int layer = 0; layer < 3; ++layer) {
    spmm_kernel<<<(N + 3) / 4, 256, 0, stream>>>(row_ptr, csr_cv,
                                                 (const float4*)cur, (float4*)nxt, N);
    gather_kernel<<<(batch + 3) / 4, 256, 0, stream>>>(u, it, nxt, accU, accI, batch, nU);
    float* t = cur; cur = nxt; nxt = t;
  }

  score_kernel<<<(batch + 3) / 4, 256, 0, stream>>>(accU, accI, (float*)d_out, batch);
}

// Round 2
// 1210.636 us; speedup vs baseline: 1.4804x; 1.3742x over previous
//
#include <hip/hip_runtime.h>

#define DIMS 64
#define SCAN_CHUNK 2048  // 256 threads * 8 elems
#define BSHIFT 10        // 1024 rows per bucket
#define BROWS (1 << BSHIFT)
#define NB_MAX 304       // >= ceil(300K/1024)=293
#define BCAP 65536       // fixed bucket capacity (mean ~34K + drain pads <54K)
#define SCAP 24          // staged entries per bucket; flush groups of 16 (64B)
#define SPITCH 25        // odd pitch -> bank-conflict-free across buckets
#define PA_THREADS 256
#define PA_K 4           // edges per thread per round (int4 vector loads)
#define PA_HALFROUND (PA_THREADS / 2 * PA_K)  // 512 edges per half per round
#define PA_HCHUNK 4096   // per-half chunk per block (8 rounds of 512)
#define PB_BLOCKS 128
#define PB_THREADS 512
#define SENTINEL 0xFFFFFFFFu

// nt 4B load (edge col stream): keep the 40MB/layer CSR stream from
// polluting L2, which stays dedicated to the hot 38MB bf16 gather target
__device__ __forceinline__ int ld_nt_int(const int* p) {
  return __builtin_nontemporal_load(p);
}

// bf16 <-> f32 helpers (storage-only bf16; all math in fp32)
__device__ __forceinline__ float bf_lo(unsigned u) {
  return __uint_as_float(u << 16);
}
__device__ __forceinline__ float bf_hi(unsigned u) {
  return __uint_as_float(u & 0xFFFF0000u);
}
__device__ __forceinline__ unsigned f2bf(float f) {  // RNE round to bf16
  unsigned u = __float_as_uint(f);
  return (u + 0x7FFFu + ((u >> 16) & 1u)) >> 16;
}

// ---------------------------------------------------------------------------
// EsS = rs * concat(U,V) stored bf16 (pre-scaled S-space embeddings)
// ---------------------------------------------------------------------------
__global__ __launch_bounds__(256) void init_es_kernel(
    const float* __restrict__ U, const float* __restrict__ V,
    const float* __restrict__ rs, unsigned short* __restrict__ Es,
    int nU_elems, int total_elems) {
  int i4 = (blockIdx.x * blockDim.x + threadIdx.x) * 4;
  if (i4 >= total_elems) return;
  float4 v = (i4 < nU_elems)
      ? *reinterpret_cast<const float4*>(U + i4)
      : *reinterpret_cast<const float4*>(V + (i4 - nU_elems));
  float s = rs[i4 >> 6];
  uint2 o;
  o.x = f2bf(v.x * s) | (f2bf(v.y * s) << 16);
  o.y = f2bf(v.z * s) | (f2bf(v.w * s) << 16);
  *reinterpret_cast<uint2*>(Es + i4) = o;
}

// ---------------------------------------------------------------------------
// Pass A: LDS-staged multisplit of packed (row_low<<19 | col) 4B entries into
// fixed-capacity row-range buckets (base = b*BCAP).
// Flush quantum = 16 entries = one full 64B line at an aligned offset.
// Each block takes one chunk from the user half AND one from the item half of
// the half-sorted symmetric COO (threads 0..127 vs 128..255) so per-round
// bucket arrival stays ~5 << SCAP.
// ---------------------------------------------------------------------------
__global__ __launch_bounds__(PA_THREADS) void pass_a_kernel(
    const int* __restrict__ rows, const int* __restrict__ cols,
    unsigned* __restrict__ temp, int* __restrict__ gcur, int nnz, int nb) {
  __shared__ unsigned stage[NB_MAX * SPITCH];
  __shared__ int scnt[NB_MAX];
  for (int b = threadIdx.x; b < nb; b += PA_THREADS) scnt[b] = 0;
  __syncthreads();

  const int half = nnz >> 1;
  const int u0 = blockIdx.x * PA_HCHUNK;
  const int u1 = min(half, u0 + PA_HCHUNK);
  const int i0 = half + blockIdx.x * PA_HCHUNK;
  const int i1 = min(nnz, i0 + PA_HCHUNK);
  const int tid = threadIdx.x;

  for (int rd = 0; rd < PA_HCHUNK / PA_HALFROUND; ++rd) {
    int base, lim;
    if (tid < PA_THREADS / 2) {
      base = u0 + rd * PA_HALFROUND + tid * PA_K;
      lim = u1;
    } else {
      base = i0 + rd * PA_HALFROUND + (tid - PA_THREADS / 2) * PA_K;
      lim = i1;
    }

    unsigned packed[PA_K];
    int bkt[PA_K];
    unsigned pend = 0;  // bitmask of entries not yet staged
    if (base + PA_K <= lim && ((base & 3) == 0)) {
      int4 r4 = *reinterpret_cast<const int4*>(rows + base);
      int4 c4 = *reinterpret_cast<const int4*>(cols + base);
      int rr[PA_K] = {r4.x, r4.y, r4.z, r4.w};
      int cc[PA_K] = {c4.x, c4.y, c4.z, c4.w};
#pragma unroll
      for (int k = 0; k < PA_K; ++k) {
        bkt[k] = rr[k] >> BSHIFT;
        packed[k] = ((unsigned)(rr[k] & (BROWS - 1)) << 19) | (unsigned)cc[k];
      }
      pend = (1u << PA_K) - 1;
    } else {
#pragma unroll
      for (int k = 0; k < PA_K; ++k) {
        int e = base + k;
        if (e < lim) {
          int r = rows[e];
          int c = cols[e];
          bkt[k] = r >> BSHIFT;
          packed[k] = ((unsigned)(r & (BROWS - 1)) << 19) | (unsigned)c;
          pend |= 1u << k;
        }
      }
    }

    for (;;) {
#pragma unroll
      for (int k = 0; k < PA_K; ++k) {
        if (pend & (1u << k)) {
          int idx = atomicAdd(&scnt[bkt[k]], 1);
          if (idx < SCAP) {
            stage[bkt[k] * SPITCH + idx] = packed[k];
            pend &= ~(1u << k);
          } else {
            atomicAdd(&scnt[bkt[k]], -1);  // undo failed claim; retry after flush
          }
        }
      }
      __syncthreads();
      // flush full 16-groups (one thread per bucket, conflict-free pitch)
      for (int bb = threadIdx.x; bb < nb; bb += PA_THREADS) {
        int cval = scnt[bb];
        if (cval >= 16) {
          int pos = atomicAdd(&gcur[bb], 16);
          unsigned v[16];
#pragma unroll
          for (int k = 0; k < 16; ++k) v[k] = stage[bb * SPITCH + k];
          uint4* dst = reinterpret_cast<uint4*>(&temp[pos]);
          dst[0] = make_uint4(v[0], v[1], v[2], v[3]);
          dst[1] = make_uint4(v[4], v[5], v[6], v[7]);
          dst[2] = make_uint4(v[8], v[9], v[10], v[11]);
          dst[3] = make_uint4(v[12], v[13], v[14], v[15]);
          for (int k = 0; k < cval - 16; ++k)
            stage[bb * SPITCH + k] = stage[bb * SPITCH + 16 + k];
          scnt[bb] = cval - 16;
        }
      }
      int pend_total = __syncthreads_count(pend ? 1 : 0);
      if (pend_total == 0) break;
    }
  }
  // final drain: pad residue to a full aligned 16-group with sentinels
  __syncthreads();
  for (int bb = threadIdx.x; bb < nb; bb += PA_THREADS) {
    int cval = scnt[bb];
    if (cval > 0) {
      int pos = atomicAdd(&gcur[bb], 16);
      for (int k = 0; k < 16; ++k)
        temp[pos + k] = (k < cval) ? stage[bb * SPITCH + k] : SENTINEL;
    }
  }
}

// ---------------------------------------------------------------------------
// Per-bucket histogram: LDS atomics + coalesced contiguous cnt stores.
// ---------------------------------------------------------------------------
__global__ __launch_bounds__(512) void hist_bucket_kernel(
    const unsigned* __restrict__ temp, const int* __restrict__ gcur,
    int* __restrict__ cnt, int n) {
  __shared__ int lcnt[BROWS];
  int b = blockIdx.x;
  int base_row = b << BSHIFT;
  int nrows = min(BROWS, n - base_row);
  for (int r = threadIdx.x; r < BROWS; r += 512) lcnt[r] = 0;
  __syncthreads();
  int start = b * BCAP, end = gcur[b];
  for (int i = start + threadIdx.x; i < end; i += 512) {
    unsigned ent = temp[i];
    if (ent != SENTINEL) atomicAdd(&lcnt[ent >> 19], 1);
  }
  __syncthreads();
  for (int r = threadIdx.x; r < nrows; r += 512)
    cnt[base_row + r] = lcnt[r];
}

// phase1: per-block chunk reduction
__global__ __launch_bounds__(256) void scan_phase1(
    const int* __restrict__ cnt, int* __restrict__ block_sums, int n) {
  __shared__ int sdata[256];
  int base = blockIdx.x * SCAN_CHUNK;
  int sum = 0;
#pragma unroll
  for (int k = 0; k < 8; ++k) {
    int idx = base + k * 256 + threadIdx.x;
    if (idx < n) sum += cnt[idx];
  }
  sdata[threadIdx.x] = sum;
  __syncthreads();
  for (int s = 128; s > 0; s >>= 1) {
    if (threadIdx.x < s) sdata[threadIdx.x] += sdata[threadIdx.x + s];
    __syncthreads();
  }
  if (threadIdx.x == 0) block_sums[blockIdx.x] = sdata[0];
}

// phase2: single 256-wide exclusive scan over block sums; writes row_ptr[n]
__global__ __launch_bounds__(256) void scan_phase2(
    int* __restrict__ block_sums, int n_blocks, int* __restrict__ row_ptr, int n) {
  __shared__ int tmp[256];
  int v = (threadIdx.x < n_blocks) ? block_sums[threadIdx.x] : 0;
  tmp[threadIdx.x] = v;
  __syncthreads();
  for (int offs = 1; offs < 256; offs <<= 1) {
    int t = (threadIdx.x >= offs) ? tmp[threadIdx.x - offs] : 0;
    __syncthreads();
    tmp[threadIdx.x] += t;
    __syncthreads();
  }
  if (threadIdx.x < n_blocks) block_sums[threadIdx.x] = tmp[threadIdx.x] - v;
  if (threadIdx.x == 0) row_ptr[n] = tmp[255];
}

// phase3: per-block chunk scan with offset, writes row_ptr
__global__ __launch_bounds__(256) void scan_phase3(
    const int* __restrict__ cnt, const int* __restrict__ block_sums,
    int* __restrict__ row_ptr, int n) {
  __shared__ int tmp[256];
  __shared__ int s_carry;
  int base = blockIdx.x * SCAN_CHUNK;
  if (threadIdx.x == 0) s_carry = block_sums[blockIdx.x];
  __syncthreads();
#pragma unroll 1
  for (int k = 0; k < 8; ++k) {
    int idx = base + k * 256 + threadIdx.x;
    int v = (idx < n) ? cnt[idx] : 0;
    tmp[threadIdx.x] = v;
    __syncthreads();
    for (int offs = 1; offs < 256; offs <<= 1) {
      int t = (threadIdx.x >= offs) ? tmp[threadIdx.x - offs] : 0;
      __syncthreads();
      tmp[threadIdx.x] += t;
      __syncthreads();
    }
    int incl = tmp[threadIdx.x];
    int carry = s_carry;
    if (idx < n) row_ptr[idx] = carry + incl - v;
    __syncthreads();
    if (threadIdx.x == 0) s_carry = carry + tmp[255];
    __syncthreads();
  }
}

// rs = 1/sqrt(deg); rs2 = rs*rs (output scale); irs = sqrt(deg) (unscale)
__global__ __launch_bounds__(256) void rs_kernel(
    const int* __restrict__ cnt, float* __restrict__ rs,
    float* __restrict__ rs2, float* __restrict__ irs, int n) {
  int i = blockIdx.x * blockDim.x + threadIdx.x;
  if (i < n) {
    float d = (float)cnt[i];
    float r = (d > 0.0f) ? 1.0f / sqrtf(d) : 1.0f;
    rs[i] = r;
    rs2[i] = r * r;
    irs[i] = (d > 0.0f) ? sqrtf(d) : 1.0f;
  }
}

// gcur init for fixed-capacity buckets
__global__ __launch_bounds__(256) void bucket_init_kernel(
    int* __restrict__ gcur, int nb) {
  int b = blockIdx.x * blockDim.x + threadIdx.x;
  if (b < nb) gcur[b] = b * BCAP;
}

// ---------------------------------------------------------------------------
// Pass B: per bucket, scatter bucket entries to exact CSR positions.
// S-space iteration needs no per-edge value: CSR payload is just the col id.
// ---------------------------------------------------------------------------
__global__ __launch_bounds__(PB_THREADS) void pass_b_kernel(
    const unsigned* __restrict__ temp, const int* __restrict__ gcur,
    const int* __restrict__ row_ptr, int* __restrict__ csr_col, int nb, int n) {
  __shared__ int ldscur[BROWS];
  for (int b = blockIdx.x; b < nb; b += gridDim.x) {
    int base_row = b << BSHIFT;
    int nrows = min(BROWS, n - base_row);
    for (int r = threadIdx.x; r < nrows; r += PB_THREADS)
      ldscur[r] = row_ptr[base_row + r];
    __syncthreads();
    int start = b * BCAP, end = gcur[b];
    for (int i = start + threadIdx.x; i < end; i += PB_THREADS) {
      unsigned ent = temp[i];
      if (ent != SENTINEL) {
        int col = (int)(ent & 0x7FFFFu);
        int rlow = (int)(ent >> 19);
        int p = atomicAdd(&ldscur[rlow], 1);
        csr_col[p] = col;
      }
    }
    __syncthreads();
  }
}

// ---------------------------------------------------------------------------
// SpMM in S-space, bf16 storage: one wave per row; the wave's four 16-lane
// quarters each gather a different edge's bf16 row as 8B (4 edges x 128B =
// 512B per instruction), unrolled 4 deep -> 16 edges outstanding per wave.
// Col stream nt-loaded. acc in fp32; epilogue applies rs2[row] and packs to
// bf16. Quarters combined with two xor-shuffles; quarter 0 stores 128B row.
// ---------------------------------------------------------------------------
__global__ __launch_bounds__(256) void spmm_kernel(
    const int* __restrict__ row_ptr, const int* __restrict__ csr_col,
    const float* __restrict__ rs2, const uint2* __restrict__ cur2,
    uint2* __restrict__ next2, int n_rows) {
  int row  = blockIdx.x * (blockDim.x >> 6) + (threadIdx.x >> 6);
  int lane = threadIdx.x & 63;
  int q    = lane >> 4;   // quarter: which edge of the group of 4
  int sub  = lane & 15;   // 8B chunk (4 bf16 dims) within the gathered row
  if (row >= n_rows) return;
  int start = row_ptr[row];
  int end   = row_ptr[row + 1];
  float4 acc = make_float4(0.0f, 0.0f, 0.0f, 0.0f);
  int e = start;
  for (; e + 16 <= end; e += 16) {
    int c0 = ld_nt_int(csr_col + e + q);
    int c1 = ld_nt_int(csr_col + e + 4 + q);
    int c2 = ld_nt_int(csr_col + e + 8 + q);
    int c3 = ld_nt_int(csr_col + e + 12 + q);
    uint2 g0 = cur2[c0 * 16 + sub];
    uint2 g1 = cur2[c1 * 16 + sub];
    uint2 g2 = cur2[c2 * 16 + sub];
    uint2 g3 = cur2[c3 * 16 + sub];
    acc.x += bf_lo(g0.x); acc.y += bf_hi(g0.x);
    acc.z += bf_lo(g0.y); acc.w += bf_hi(g0.y);
    acc.x += bf_lo(g1.x); acc.y += bf_hi(g1.x);
    acc.z += bf_lo(g1.y); acc.w += bf_hi(g1.y);
    acc.x += bf_lo(g2.x); acc.y += bf_hi(g2.x);
    acc.z += bf_lo(g2.y); acc.w += bf_hi(g2.y);
    acc.x += bf_lo(g3.x); acc.y += bf_hi(g3.x);
    acc.z += bf_lo(g3.y); acc.w += bf_hi(g3.y);
  }
  for (; e + 4 <= end; e += 4) {
    int c = ld_nt_int(csr_col + e + q);
    uint2 g = cur2[c * 16 + sub];
    acc.x += bf_lo(g.x); acc.y += bf_hi(g.x);
    acc.z += bf_lo(g.y); acc.w += bf_hi(g.y);
  }
  if (e < end) {  // 1..3 remaining: masked quarters
    int idx = min(e + q, end - 1);
    int c = ld_nt_int(csr_col + idx);
    uint2 g = cur2[c * 16 + sub];
    if (e + q < end) {
      acc.x += bf_lo(g.x); acc.y += bf_hi(g.x);
      acc.z += bf_lo(g.y); acc.w += bf_hi(g.y);
    }
  }
  // combine the four quarter partial sums
#pragma unroll
  for (int offs = 16; offs <= 32; offs <<= 1) {
    acc.x += __shfl_xor(acc.x, offs, 64);
    acc.y += __shfl_xor(acc.y, offs, 64);
    acc.z += __shfl_xor(acc.z, offs, 64);
    acc.w += __shfl_xor(acc.w, offs, 64);
  }
  if (q == 0) {
    float s = rs2[row];
    uint2 o;
    o.x = f2bf(acc.x * s) | (f2bf(acc.y * s) << 16);
    o.y = f2bf(acc.z * s) | (f2bf(acc.w * s) << 16);
    next2[row * 16 + sub] = o;
  }
}

// ---------------------------------------------------------------------------
// Layer-0 batch gather: exact fp32 E0 rows straight from U/V (initializes acc)
// ---------------------------------------------------------------------------
__global__ __launch_bounds__(256) void gather0_kernel(
    const int* __restrict__ u, const int* __restrict__ it,
    const float* __restrict__ U, const float* __restrict__ V,
    float* __restrict__ accU, float* __restrict__ accI, int batch) {
  int b    = blockIdx.x * (blockDim.x >> 6) + (threadIdx.x >> 6);
  int lane = threadIdx.x & 63;
  if (b >= batch) return;
  accU[b * DIMS + lane] = U[u[b] * DIMS + lane];
  accI[b * DIMS + lane] = V[it[b] * DIMS + lane];
}

// Layer-k batch gather from S-space bf16: unscale by irs = sqrt(deg)
__global__ __launch_bounds__(256) void gather_s_kernel(
    const int* __restrict__ u, const int* __restrict__ it,
    const unsigned short* __restrict__ curS, const float* __restrict__ irs,
    float* __restrict__ accU, float* __restrict__ accI, int batch, int nU) {
  int b    = blockIdx.x * (blockDim.x >> 6) + (threadIdx.x >> 6);
  int lane = threadIdx.x & 63;
  if (b >= batch) return;
  int ru = u[b];
  int ri = it[b] + nU;
  accU[b * DIMS + lane] +=
      __uint_as_float((unsigned)curS[ru * DIMS + lane] << 16) * irs[ru];
  accI[b * DIMS + lane] +=
      __uint_as_float((unsigned)curS[ri * DIMS + lane] << 16) * irs[ri];
}

__global__ __launch_bounds__(256) void score_kernel(
    const float* __restrict__ accU, const float* __restrict__ accI,
    float* __restrict__ out, int batch) {
  int b    = blockIdx.x * (blockDim.x >> 6) + (threadIdx.x >> 6);
  int lane = threadIdx.x & 63;
  if (b >= batch) return;
  float v = accU[b * DIMS + lane] * accI[b * DIMS + lane];
  for (int offs = 32; offs > 0; offs >>= 1) v += __shfl_down(v, offs, 64);
  if (lane == 0) out[b] = v * (1.0f / 16.0f);
}

// ---------------------------------------------------------------------------
extern "C" void kernel_launch(void* const* d_in, const int* in_sizes, int n_in,
                              void* d_out, int out_size, void* d_ws, size_t ws_size,
                              hipStream_t stream) {
  const int*   u     = (const int*)d_in[0];
  const int*   it    = (const int*)d_in[1];
  const int*   arows = (const int*)d_in[2];
  const int*   acols = (const int*)d_in[3];
  const float* U     = (const float*)d_in[5];
  const float* V     = (const float*)d_in[6];

  const int batch = in_sizes[0];
  const int nnz   = in_sizes[2];
  const int nU    = in_sizes[5] / DIMS;
  const int nV    = in_sizes[6] / DIMS;
  const int N     = nU + nV;
  const int n_scan_blocks = (N + SCAN_CHUNK - 1) / SCAN_CHUNK;
  const int NB    = (N + BROWS - 1) >> BSHIFT;  // 293
  const size_t esbytes = (size_t)N * DIMS * 2;  // bf16 embeddings
  const size_t tbytes  = (size_t)NB * BCAP * 4;
  const size_t xbytes  = tbytes > esbytes ? tbytes : esbytes;

  // pass_a grid: each block covers one PA_HCHUNK chunk of EACH half
  const int big_half = nnz - nnz / 2;
  const int PA_B = (big_half + PA_HCHUNK - 1) / PA_HCHUNK;

  char*  ws  = (char*)d_ws;
  size_t off = 0;
  auto take = [&](size_t bytes) -> void* {
    void* p = ws + off;
    off = (off + bytes + 255) & ~(size_t)255;
    return p;
  };
  int*     cnt        = (int*)take((size_t)N * 4);
  float*   rs         = (float*)take((size_t)N * 4);
  float*   rs2        = (float*)take((size_t)N * 4);
  float*   irs        = (float*)take((size_t)N * 4);
  int*     row_ptr    = (int*)take((size_t)(N + 1) * 4);
  int*     block_sums = (int*)take((size_t)256 * 4);
  int*     gcur       = (int*)take((size_t)NB * 4);
  int*     csr_col    = (int*)take((size_t)nnz * 4);
  char*    X          = (char*)take(xbytes);   // temp (build), then bufA (Es)
  unsigned short* bufB = (unsigned short*)take(esbytes);
  float*   accU       = (float*)take((size_t)batch * DIMS * 4);
  float*   accI       = (float*)take((size_t)batch * DIMS * 4);
  unsigned* temp      = (unsigned*)X;
  unsigned short* bufA = (unsigned short*)X;

  // ---- CSR build (uses X as temp) ----
  bucket_init_kernel<<<(NB + 255) / 256, 256, 0, stream>>>(gcur, NB);
  pass_a_kernel<<<PA_B, PA_THREADS, 0, stream>>>(arows, acols, temp, gcur, nnz, NB);
  hist_bucket_kernel<<<NB, 512, 0, stream>>>(temp, gcur, cnt, N);
  scan_phase1<<<n_scan_blocks, 256, 0, stream>>>(cnt, block_sums, N);
  scan_phase2<<<1, 256, 0, stream>>>(block_sums, n_scan_blocks, row_ptr, N);
  scan_phase3<<<n_scan_blocks, 256, 0, stream>>>(cnt, block_sums, row_ptr, N);
  rs_kernel<<<(N + 255) / 256, 256, 0, stream>>>(cnt, rs, rs2, irs, N);
  pass_b_kernel<<<PB_BLOCKS, PB_THREADS, 0, stream>>>(temp, gcur, row_ptr,
                                                      csr_col, NB, N);

  // ---- batch acc init with exact fp32 E0 rows ----
  gather0_kernel<<<(batch + 3) / 4, 256, 0, stream>>>(u, it, U, V, accU, accI,
                                                      batch);

  // ---- Es0 = rs * E0 in bf16 (X becomes bufA now that temp is dead) ----
  {
    int total = N * DIMS;
    int t4 = total / 4;
    init_es_kernel<<<(t4 + 255) / 256, 256, 0, stream>>>(U, V, rs, bufA,
                                                         nU * DIMS, total);
  }

  unsigned short* cur = bufA;
  unsigned short* nxt = bufB;
  for (int layer = 0; layer < 3; ++layer) {
    spmm_kernel<<<(N + 3) / 4, 256, 0, stream>>>(
        row_ptr, csr_col, rs2, (const uint2*)cur, (uint2*)nxt, N);
    gather_s_kernel<<<(batch + 3) / 4, 256, 0, stream>>>(u, it, nxt, irs, accU,
                                                         accI, batch, nU);
    unsigned short* t = cur; cur = nxt; nxt = t;
  }

  score_kernel<<<(batch + 3) / 4, 256, 0, stream>>>(accU, accI, (float*)d_out, batch);
}

// Round 3
// 1109.624 us; speedup vs baseline: 1.6152x; 1.0910x over previous
//
#include <hip/hip_runtime.h>

#define DIMS 64
#define SCAN_CHUNK 2048  // 256 threads * 8 elems
#define BSHIFT 10        // 1024 rows per bucket
#define BROWS (1 << BSHIFT)
#define NB_MAX 304       // >= ceil(300K/1024)=293
#define BCAP 65536       // fixed bucket capacity (mean ~34K + drain pads <54K)
#define SCAP 24          // staged entries per bucket; flush groups of 16 (64B)
#define SPITCH 25        // odd pitch -> bank-conflict-free across buckets
#define PA_THREADS 256
#define PA_K 4           // edges per thread per round (int4 vector loads)
#define PA_HALFROUND (PA_THREADS / 2 * PA_K)  // 512 edges per half per round
#define PA_HCHUNK 4096   // per-half chunk per block (8 rounds of 512)
#define PB_BLOCKS 128
#define PB_THREADS 512
#define SENTINEL 0xFFFFFFFFu

// nt 4B load (edge col stream): keep the 40MB/layer CSR stream from
// polluting L2, which stays dedicated to the hot 38MB bf16 gather target
__device__ __forceinline__ int ld_nt_int(const int* p) {
  return __builtin_nontemporal_load(p);
}

// bf16 <-> f32 helpers (storage-only bf16; all math in fp32)
__device__ __forceinline__ float bf_lo(unsigned u) {
  return __uint_as_float(u << 16);
}
__device__ __forceinline__ float bf_hi(unsigned u) {
  return __uint_as_float(u & 0xFFFF0000u);
}
__device__ __forceinline__ unsigned f2bf(float f) {  // RNE round to bf16
  unsigned u = __float_as_uint(f);
  return (u + 0x7FFFu + ((u >> 16) & 1u)) >> 16;
}

// ---------------------------------------------------------------------------
// Es0 = rs * concat(U,V) stored bf16 (pre-scaled S-space embeddings)
// ---------------------------------------------------------------------------
__global__ __launch_bounds__(256) void init_es_kernel(
    const float* __restrict__ U, const float* __restrict__ V,
    const float* __restrict__ rs, unsigned short* __restrict__ Es,
    int nU_elems, int total_elems) {
  int i4 = (blockIdx.x * blockDim.x + threadIdx.x) * 4;
  if (i4 >= total_elems) return;
  float4 v = (i4 < nU_elems)
      ? *reinterpret_cast<const float4*>(U + i4)
      : *reinterpret_cast<const float4*>(V + (i4 - nU_elems));
  float s = rs[i4 >> 6];
  uint2 o;
  o.x = f2bf(v.x * s) | (f2bf(v.y * s) << 16);
  o.y = f2bf(v.z * s) | (f2bf(v.w * s) << 16);
  *reinterpret_cast<uint2*>(Es + i4) = o;
}

// ---------------------------------------------------------------------------
// Pass A: LDS-staged multisplit of packed (row_low<<19 | col) 4B entries into
// fixed-capacity row-range buckets (base = b*BCAP).
// Flush quantum = 16 entries = one full 64B line at an aligned offset.
// Each block takes one chunk from the user half AND one from the item half of
// the half-range-split symmetric COO (threads 0..127 vs 128..255) so
// per-round bucket arrival stays ~5 << SCAP.
// ---------------------------------------------------------------------------
__global__ __launch_bounds__(PA_THREADS) void pass_a_kernel(
    const int* __restrict__ rows, const int* __restrict__ cols,
    unsigned* __restrict__ temp, int* __restrict__ gcur, int nnz, int nb) {
  __shared__ unsigned stage[NB_MAX * SPITCH];
  __shared__ int scnt[NB_MAX];
  for (int b = threadIdx.x; b < nb; b += PA_THREADS) scnt[b] = 0;
  __syncthreads();

  const int half = nnz >> 1;
  const int u0 = blockIdx.x * PA_HCHUNK;
  const int u1 = min(half, u0 + PA_HCHUNK);
  const int i0 = half + blockIdx.x * PA_HCHUNK;
  const int i1 = min(nnz, i0 + PA_HCHUNK);
  const int tid = threadIdx.x;

  for (int rd = 0; rd < PA_HCHUNK / PA_HALFROUND; ++rd) {
    int base, lim;
    if (tid < PA_THREADS / 2) {
      base = u0 + rd * PA_HALFROUND + tid * PA_K;
      lim = u1;
    } else {
      base = i0 + rd * PA_HALFROUND + (tid - PA_THREADS / 2) * PA_K;
      lim = i1;
    }

    unsigned packed[PA_K];
    int bkt[PA_K];
    unsigned pend = 0;  // bitmask of entries not yet staged
    if (base + PA_K <= lim && ((base & 3) == 0)) {
      int4 r4 = *reinterpret_cast<const int4*>(rows + base);
      int4 c4 = *reinterpret_cast<const int4*>(cols + base);
      int rr[PA_K] = {r4.x, r4.y, r4.z, r4.w};
      int cc[PA_K] = {c4.x, c4.y, c4.z, c4.w};
#pragma unroll
      for (int k = 0; k < PA_K; ++k) {
        bkt[k] = rr[k] >> BSHIFT;
        packed[k] = ((unsigned)(rr[k] & (BROWS - 1)) << 19) | (unsigned)cc[k];
      }
      pend = (1u << PA_K) - 1;
    } else {
#pragma unroll
      for (int k = 0; k < PA_K; ++k) {
        int e = base + k;
        if (e < lim) {
          int r = rows[e];
          int c = cols[e];
          bkt[k] = r >> BSHIFT;
          packed[k] = ((unsigned)(r & (BROWS - 1)) << 19) | (unsigned)c;
          pend |= 1u << k;
        }
      }
    }

    for (;;) {
#pragma unroll
      for (int k = 0; k < PA_K; ++k) {
        if (pend & (1u << k)) {
          int idx = atomicAdd(&scnt[bkt[k]], 1);
          if (idx < SCAP) {
            stage[bkt[k] * SPITCH + idx] = packed[k];
            pend &= ~(1u << k);
          } else {
            atomicAdd(&scnt[bkt[k]], -1);  // undo failed claim; retry after flush
          }
        }
      }
      __syncthreads();
      // flush full 16-groups (one thread per bucket, conflict-free pitch)
      for (int bb = threadIdx.x; bb < nb; bb += PA_THREADS) {
        int cval = scnt[bb];
        if (cval >= 16) {
          int pos = atomicAdd(&gcur[bb], 16);
          unsigned v[16];
#pragma unroll
          for (int k = 0; k < 16; ++k) v[k] = stage[bb * SPITCH + k];
          uint4* dst = reinterpret_cast<uint4*>(&temp[pos]);
          dst[0] = make_uint4(v[0], v[1], v[2], v[3]);
          dst[1] = make_uint4(v[4], v[5], v[6], v[7]);
          dst[2] = make_uint4(v[8], v[9], v[10], v[11]);
          dst[3] = make_uint4(v[12], v[13], v[14], v[15]);
          for (int k = 0; k < cval - 16; ++k)
            stage[bb * SPITCH + k] = stage[bb * SPITCH + 16 + k];
          scnt[bb] = cval - 16;
        }
      }
      int pend_total = __syncthreads_count(pend ? 1 : 0);
      if (pend_total == 0) break;
    }
  }
  // final drain: pad residue to a full aligned 16-group with sentinels
  __syncthreads();
  for (int bb = threadIdx.x; bb < nb; bb += PA_THREADS) {
    int cval = scnt[bb];
    if (cval > 0) {
      int pos = atomicAdd(&gcur[bb], 16);
      for (int k = 0; k < 16; ++k)
        temp[pos + k] = (k < cval) ? stage[bb * SPITCH + k] : SENTINEL;
    }
  }
}

// ---------------------------------------------------------------------------
// Per-bucket histogram: LDS atomics + coalesced contiguous cnt stores.
// ---------------------------------------------------------------------------
__global__ __launch_bounds__(512) void hist_bucket_kernel(
    const unsigned* __restrict__ temp, const int* __restrict__ gcur,
    int* __restrict__ cnt, int n) {
  __shared__ int lcnt[BROWS];
  int b = blockIdx.x;
  int base_row = b << BSHIFT;
  int nrows = min(BROWS, n - base_row);
  for (int r = threadIdx.x; r < BROWS; r += 512) lcnt[r] = 0;
  __syncthreads();
  int start = b * BCAP, end = gcur[b];
  for (int i = start + threadIdx.x; i < end; i += 512) {
    unsigned ent = temp[i];
    if (ent != SENTINEL) atomicAdd(&lcnt[ent >> 19], 1);
  }
  __syncthreads();
  for (int r = threadIdx.x; r < nrows; r += 512)
    cnt[base_row + r] = lcnt[r];
}

// phase1: per-block chunk reduction
__global__ __launch_bounds__(256) void scan_phase1(
    const int* __restrict__ cnt, int* __restrict__ block_sums, int n) {
  __shared__ int sdata[256];
  int base = blockIdx.x * SCAN_CHUNK;
  int sum = 0;
#pragma unroll
  for (int k = 0; k < 8; ++k) {
    int idx = base + k * 256 + threadIdx.x;
    if (idx < n) sum += cnt[idx];
  }
  sdata[threadIdx.x] = sum;
  __syncthreads();
  for (int s = 128; s > 0; s >>= 1) {
    if (threadIdx.x < s) sdata[threadIdx.x] += sdata[threadIdx.x + s];
    __syncthreads();
  }
  if (threadIdx.x == 0) block_sums[blockIdx.x] = sdata[0];
}

// phase2: single 256-wide exclusive scan over block sums; writes row_ptr[n]
__global__ __launch_bounds__(256) void scan_phase2(
    int* __restrict__ block_sums, int n_blocks, int* __restrict__ row_ptr, int n) {
  __shared__ int tmp[256];
  int v = (threadIdx.x < n_blocks) ? block_sums[threadIdx.x] : 0;
  tmp[threadIdx.x] = v;
  __syncthreads();
  for (int offs = 1; offs < 256; offs <<= 1) {
    int t = (threadIdx.x >= offs) ? tmp[threadIdx.x - offs] : 0;
    __syncthreads();
    tmp[threadIdx.x] += t;
    __syncthreads();
  }
  if (threadIdx.x < n_blocks) block_sums[threadIdx.x] = tmp[threadIdx.x] - v;
  if (threadIdx.x == 0) row_ptr[n] = tmp[255];
}

// phase3: per-block chunk scan with offset, writes row_ptr
__global__ __launch_bounds__(256) void scan_phase3(
    const int* __restrict__ cnt, const int* __restrict__ block_sums,
    int* __restrict__ row_ptr, int n) {
  __shared__ int tmp[256];
  __shared__ int s_carry;
  int base = blockIdx.x * SCAN_CHUNK;
  if (threadIdx.x == 0) s_carry = block_sums[blockIdx.x];
  __syncthreads();
#pragma unroll 1
  for (int k = 0; k < 8; ++k) {
    int idx = base + k * 256 + threadIdx.x;
    int v = (idx < n) ? cnt[idx] : 0;
    tmp[threadIdx.x] = v;
    __syncthreads();
    for (int offs = 1; offs < 256; offs <<= 1) {
      int t = (threadIdx.x >= offs) ? tmp[threadIdx.x - offs] : 0;
      __syncthreads();
      tmp[threadIdx.x] += t;
      __syncthreads();
    }
    int incl = tmp[threadIdx.x];
    int carry = s_carry;
    if (idx < n) row_ptr[idx] = carry + incl - v;
    __syncthreads();
    if (threadIdx.x == 0) s_carry = carry + tmp[255];
    __syncthreads();
  }
}

// rs = 1/sqrt(deg); rs2 = rs*rs (output scale); irs = sqrt(deg) (unscale)
__global__ __launch_bounds__(256) void rs_kernel(
    const int* __restrict__ cnt, float* __restrict__ rs,
    float* __restrict__ rs2, float* __restrict__ irs, int n) {
  int i = blockIdx.x * blockDim.x + threadIdx.x;
  if (i < n) {
    float d = (float)cnt[i];
    float r = (d > 0.0f) ? 1.0f / sqrtf(d) : 1.0f;
    rs[i] = r;
    rs2[i] = r * r;
    irs[i] = (d > 0.0f) ? sqrtf(d) : 1.0f;
  }
}

// gcur init for fixed-capacity buckets
__global__ __launch_bounds__(256) void bucket_init_kernel(
    int* __restrict__ gcur, int nb) {
  int b = blockIdx.x * blockDim.x + threadIdx.x;
  if (b < nb) gcur[b] = b * BCAP;
}

// ---------------------------------------------------------------------------
// Pass B: per bucket, scatter bucket entries to exact CSR positions.
// S-space iteration needs no per-edge value: CSR payload is just the col id.
// ---------------------------------------------------------------------------
__global__ __launch_bounds__(PB_THREADS) void pass_b_kernel(
    const unsigned* __restrict__ temp, const int* __restrict__ gcur,
    const int* __restrict__ row_ptr, int* __restrict__ csr_col, int nb, int n) {
  __shared__ int ldscur[BROWS];
  for (int b = blockIdx.x; b < nb; b += gridDim.x) {
    int base_row = b << BSHIFT;
    int nrows = min(BROWS, n - base_row);
    for (int r = threadIdx.x; r < nrows; r += PB_THREADS)
      ldscur[r] = row_ptr[base_row + r];
    __syncthreads();
    int start = b * BCAP, end = gcur[b];
    for (int i = start + threadIdx.x; i < end; i += PB_THREADS) {
      unsigned ent = temp[i];
      if (ent != SENTINEL) {
        int col = (int)(ent & 0x7FFFFu);
        int rlow = (int)(ent >> 19);
        int p = atomicAdd(&ldscur[rlow], 1);
        csr_col[p] = col;
      }
    }
    __syncthreads();
  }
}

// ---------------------------------------------------------------------------
// SpMM in S-space, bf16 storage: one wave per row; the wave's four 16-lane
// quarters each gather a different edge's bf16 row as 8B. Main loop keeps 8
// gathers (32 edges) outstanding per wave. Col stream nt-loaded. acc in fp32;
// epilogue applies rs2[row] and packs to bf16; quarter 0 stores the 128B row.
// ---------------------------------------------------------------------------
__global__ __launch_bounds__(256) void spmm_kernel(
    const int* __restrict__ row_ptr, const int* __restrict__ csr_col,
    const float* __restrict__ rs2, const uint2* __restrict__ cur2,
    uint2* __restrict__ next2, int n_rows) {
  int row  = blockIdx.x * (blockDim.x >> 6) + (threadIdx.x >> 6);
  int lane = threadIdx.x & 63;
  int q    = lane >> 4;   // quarter: which edge of the group of 4
  int sub  = lane & 15;   // 8B chunk (4 bf16 dims) within the gathered row
  if (row >= n_rows) return;
  int start = row_ptr[row];
  int end   = row_ptr[row + 1];
  float4 acc = make_float4(0.0f, 0.0f, 0.0f, 0.0f);
  int e = start;
  for (; e + 32 <= end; e += 32) {
    int c[8];
    uint2 g[8];
#pragma unroll
    for (int k = 0; k < 8; ++k) c[k] = ld_nt_int(csr_col + e + 4 * k + q);
#pragma unroll
    for (int k = 0; k < 8; ++k) g[k] = cur2[c[k] * 16 + sub];
#pragma unroll
    for (int k = 0; k < 8; ++k) {
      acc.x += bf_lo(g[k].x); acc.y += bf_hi(g[k].x);
      acc.z += bf_lo(g[k].y); acc.w += bf_hi(g[k].y);
    }
  }
  for (; e + 4 <= end; e += 4) {
    int c = ld_nt_int(csr_col + e + q);
    uint2 g = cur2[c * 16 + sub];
    acc.x += bf_lo(g.x); acc.y += bf_hi(g.x);
    acc.z += bf_lo(g.y); acc.w += bf_hi(g.y);
  }
  if (e < end) {  // 1..3 remaining: masked quarters
    int idx = min(e + q, end - 1);
    int c = ld_nt_int(csr_col + idx);
    uint2 g = cur2[c * 16 + sub];
    if (e + q < end) {
      acc.x += bf_lo(g.x); acc.y += bf_hi(g.x);
      acc.z += bf_lo(g.y); acc.w += bf_hi(g.y);
    }
  }
  // combine the four quarter partial sums
#pragma unroll
  for (int offs = 16; offs <= 32; offs <<= 1) {
    acc.x += __shfl_xor(acc.x, offs, 64);
    acc.y += __shfl_xor(acc.y, offs, 64);
    acc.z += __shfl_xor(acc.z, offs, 64);
    acc.w += __shfl_xor(acc.w, offs, 64);
  }
  if (q == 0) {
    float s = rs2[row];
    uint2 o;
    o.x = f2bf(acc.x * s) | (f2bf(acc.y * s) << 16);
    o.y = f2bf(acc.z * s) | (f2bf(acc.w * s) << 16);
    next2[row * 16 + sub] = o;
  }
}

// ---------------------------------------------------------------------------
// Layer-3 batch-restricted SpMM: only the 2*batch rows needed by the output.
// acc[b] += rs[row] * sum_{c in N(row)} S2[c]   (== gather(E3) exactly)
// One wave per (batch-slot, side) task; same quarter-gather inner loop.
// ---------------------------------------------------------------------------
__global__ __launch_bounds__(256) void batch_spmm_kernel(
    const int* __restrict__ u, const int* __restrict__ it,
    const int* __restrict__ row_ptr, const int* __restrict__ csr_col,
    const float* __restrict__ rs, const uint2* __restrict__ cur2,
    float* __restrict__ accU, float* __restrict__ accI, int batch, int nU) {
  int t    = blockIdx.x * (blockDim.x >> 6) + (threadIdx.x >> 6);
  int lane = threadIdx.x & 63;
  int q    = lane >> 4;
  int sub  = lane & 15;
  if (t >= 2 * batch) return;
  int b = t >> 1;
  bool uside = (t & 1) == 0;
  int row = uside ? u[b] : (it[b] + nU);
  int start = row_ptr[row];
  int end   = row_ptr[row + 1];
  float4 acc = make_float4(0.0f, 0.0f, 0.0f, 0.0f);
  int e = start;
  for (; e + 16 <= end; e += 16) {
    int c[4];
    uint2 g[4];
#pragma unroll
    for (int k = 0; k < 4; ++k) c[k] = ld_nt_int(csr_col + e + 4 * k + q);
#pragma unroll
    for (int k = 0; k < 4; ++k) g[k] = cur2[c[k] * 16 + sub];
#pragma unroll
    for (int k = 0; k < 4; ++k) {
      acc.x += bf_lo(g[k].x); acc.y += bf_hi(g[k].x);
      acc.z += bf_lo(g[k].y); acc.w += bf_hi(g[k].y);
    }
  }
  for (; e + 4 <= end; e += 4) {
    int c = ld_nt_int(csr_col + e + q);
    uint2 g = cur2[c * 16 + sub];
    acc.x += bf_lo(g.x); acc.y += bf_hi(g.x);
    acc.z += bf_lo(g.y); acc.w += bf_hi(g.y);
  }
  if (e < end) {
    int idx = min(e + q, end - 1);
    int c = ld_nt_int(csr_col + idx);
    uint2 g = cur2[c * 16 + sub];
    if (e + q < end) {
      acc.x += bf_lo(g.x); acc.y += bf_hi(g.x);
      acc.z += bf_lo(g.y); acc.w += bf_hi(g.y);
    }
  }
#pragma unroll
  for (int offs = 16; offs <= 32; offs <<= 1) {
    acc.x += __shfl_xor(acc.x, offs, 64);
    acc.y += __shfl_xor(acc.y, offs, 64);
    acc.z += __shfl_xor(acc.z, offs, 64);
    acc.w += __shfl_xor(acc.w, offs, 64);
  }
  if (q == 0) {
    float s = rs[row];
    float* dst = (uside ? accU : accI) + (size_t)b * DIMS + sub * 4;
    float4 old = *reinterpret_cast<float4*>(dst);
    old.x += acc.x * s; old.y += acc.y * s;
    old.z += acc.z * s; old.w += acc.w * s;
    *reinterpret_cast<float4*>(dst) = old;
  }
}

// ---------------------------------------------------------------------------
// Layer-0 batch gather: exact fp32 E0 rows straight from U/V (initializes acc)
// ---------------------------------------------------------------------------
__global__ __launch_bounds__(256) void gather0_kernel(
    const int* __restrict__ u, const int* __restrict__ it,
    const float* __restrict__ U, const float* __restrict__ V,
    float* __restrict__ accU, float* __restrict__ accI, int batch) {
  int b    = blockIdx.x * (blockDim.x >> 6) + (threadIdx.x >> 6);
  int lane = threadIdx.x & 63;
  if (b >= batch) return;
  accU[b * DIMS + lane] = U[u[b] * DIMS + lane];
  accI[b * DIMS + lane] = V[it[b] * DIMS + lane];
}

// Layer-k batch gather from S-space bf16: unscale by irs = sqrt(deg)
__global__ __launch_bounds__(256) void gather_s_kernel(
    const int* __restrict__ u, const int* __restrict__ it,
    const unsigned short* __restrict__ curS, const float* __restrict__ irs,
    float* __restrict__ accU, float* __restrict__ accI, int batch, int nU) {
  int b    = blockIdx.x * (blockDim.x >> 6) + (threadIdx.x >> 6);
  int lane = threadIdx.x & 63;
  if (b >= batch) return;
  int ru = u[b];
  int ri = it[b] + nU;
  accU[b * DIMS + lane] +=
      __uint_as_float((unsigned)curS[ru * DIMS + lane] << 16) * irs[ru];
  accI[b * DIMS + lane] +=
      __uint_as_float((unsigned)curS[ri * DIMS + lane] << 16) * irs[ri];
}

__global__ __launch_bounds__(256) void score_kernel(
    const float* __restrict__ accU, const float* __restrict__ accI,
    float* __restrict__ out, int batch) {
  int b    = blockIdx.x * (blockDim.x >> 6) + (threadIdx.x >> 6);
  int lane = threadIdx.x & 63;
  if (b >= batch) return;
  float v = accU[b * DIMS + lane] * accI[b * DIMS + lane];
  for (int offs = 32; offs > 0; offs >>= 1) v += __shfl_down(v, offs, 64);
  if (lane == 0) out[b] = v * (1.0f / 16.0f);
}

// ---------------------------------------------------------------------------
extern "C" void kernel_launch(void* const* d_in, const int* in_sizes, int n_in,
                              void* d_out, int out_size, void* d_ws, size_t ws_size,
                              hipStream_t stream) {
  const int*   u     = (const int*)d_in[0];
  const int*   it    = (const int*)d_in[1];
  const int*   arows = (const int*)d_in[2];
  const int*   acols = (const int*)d_in[3];
  const float* U     = (const float*)d_in[5];
  const float* V     = (const float*)d_in[6];

  const int batch = in_sizes[0];
  const int nnz   = in_sizes[2];
  const int nU    = in_sizes[5] / DIMS;
  const int nV    = in_sizes[6] / DIMS;
  const int N     = nU + nV;
  const int n_scan_blocks = (N + SCAN_CHUNK - 1) / SCAN_CHUNK;
  const int NB    = (N + BROWS - 1) >> BSHIFT;  // 293
  const size_t esbytes = (size_t)N * DIMS * 2;  // bf16 embeddings
  const size_t tbytes  = (size_t)NB * BCAP * 4;
  const size_t xbytes  = tbytes > esbytes ? tbytes : esbytes;

  // pass_a grid: each block covers one PA_HCHUNK chunk of EACH half
  const int big_half = nnz - nnz / 2;
  const int PA_B = (big_half + PA_HCHUNK - 1) / PA_HCHUNK;

  char*  ws  = (char*)d_ws;
  size_t off = 0;
  auto take = [&](size_t bytes) -> void* {
    void* p = ws + off;
    off = (off + bytes + 255) & ~(size_t)255;
    return p;
  };
  int*     cnt        = (int*)take((size_t)N * 4);
  float*   rs         = (float*)take((size_t)N * 4);
  float*   rs2        = (float*)take((size_t)N * 4);
  float*   irs        = (float*)take((size_t)N * 4);
  int*     row_ptr    = (int*)take((size_t)(N + 1) * 4);
  int*     block_sums = (int*)take((size_t)256 * 4);
  int*     gcur       = (int*)take((size_t)NB * 4);
  int*     csr_col    = (int*)take((size_t)nnz * 4);
  char*    X          = (char*)take(xbytes);   // temp (build), then bufA (Es)
  unsigned short* bufB = (unsigned short*)take(esbytes);
  float*   accU       = (float*)take((size_t)batch * DIMS * 4);
  float*   accI       = (float*)take((size_t)batch * DIMS * 4);
  unsigned* temp      = (unsigned*)X;
  unsigned short* bufA = (unsigned short*)X;

  // ---- CSR build (uses X as temp) ----
  bucket_init_kernel<<<(NB + 255) / 256, 256, 0, stream>>>(gcur, NB);
  pass_a_kernel<<<PA_B, PA_THREADS, 0, stream>>>(arows, acols, temp, gcur, nnz, NB);
  hist_bucket_kernel<<<NB, 512, 0, stream>>>(temp, gcur, cnt, N);
  scan_phase1<<<n_scan_blocks, 256, 0, stream>>>(cnt, block_sums, N);
  scan_phase2<<<1, 256, 0, stream>>>(block_sums, n_scan_blocks, row_ptr, N);
  scan_phase3<<<n_scan_blocks, 256, 0, stream>>>(cnt, block_sums, row_ptr, N);
  rs_kernel<<<(N + 255) / 256, 256, 0, stream>>>(cnt, rs, rs2, irs, N);
  pass_b_kernel<<<PB_BLOCKS, PB_THREADS, 0, stream>>>(temp, gcur, row_ptr,
                                                      csr_col, NB, N);

  // ---- batch acc init with exact fp32 E0 rows ----
  gather0_kernel<<<(batch + 3) / 4, 256, 0, stream>>>(u, it, U, V, accU, accI,
                                                      batch);

  // ---- Es0 = rs * E0 in bf16 (X becomes bufA now that temp is dead) ----
  {
    int total = N * DIMS;
    int t4 = total / 4;
    init_es_kernel<<<(t4 + 255) / 256, 256, 0, stream>>>(U, V, rs, bufA,
                                                         nU * DIMS, total);
  }

  // ---- layers 1,2: full SpMM + batch gather; layer 3: batch-restricted ----
  unsigned short* cur = bufA;
  unsigned short* nxt = bufB;
  for (int layer = 0; layer < 2; ++layer) {
    spmm_kernel<<<(N + 3) / 4, 256, 0, stream>>>(
        row_ptr, csr_col, rs2, (const uint2*)cur, (uint2*)nxt, N);
    gather_s_kernel<<<(batch + 3) / 4, 256, 0, stream>>>(u, it, nxt, irs, accU,
                                                         accI, batch, nU);
    unsigned short* t = cur; cur = nxt; nxt = t;
  }
  batch_spmm_kernel<<<(2 * batch + 3) / 4, 256, 0, stream>>>(
      u, it, row_ptr, csr_col, rs, (const uint2*)cur, accU, accI, batch, nU);

  score_kernel<<<(batch + 3) / 4, 256, 0, stream>>>(accU, accI, (float*)d_out, batch);
}

// Round 4
// 923.016 us; speedup vs baseline: 1.9418x; 1.2022x over previous
//
#include <hip/hip_runtime.h>

#define DIMS 64
#define SCAN_CHUNK 2048  // 256 threads * 8 elems
#define BSHIFT 10        // 1024 rows per bucket
#define BROWS (1 << BSHIFT)
#define NB_MAX 304       // >= ceil(300K/1024)=293
#define BCAP 65536       // fixed bucket capacity (mean ~34K + drain pads <54K)
#define SCAP 24          // staged entries per bucket; flush groups of 16 (64B)
#define SPITCH 25        // odd pitch -> bank-conflict-free across buckets
#define PA_THREADS 256
#define PA_K 4           // edges per thread per round (int4 vector loads)
#define PA_HALFROUND (PA_THREADS / 2 * PA_K)  // 512 edges per half per round
#define PA_HCHUNK 4096   // per-half chunk per block (8 rounds of 512)
#define PB_THREADS 512
#define SENTINEL 0xFFFFFFFFu

// nt 4B load (edge col stream): keep the 40MB/layer CSR stream from
// polluting L2, which stays dedicated to the hot 38MB bf16 gather target
__device__ __forceinline__ int ld_nt_int(const int* p) {
  return __builtin_nontemporal_load(p);
}

// bf16 <-> f32 helpers (storage-only bf16; all math in fp32)
__device__ __forceinline__ float bf_lo(unsigned u) {
  return __uint_as_float(u << 16);
}
__device__ __forceinline__ float bf_hi(unsigned u) {
  return __uint_as_float(u & 0xFFFF0000u);
}
__device__ __forceinline__ unsigned f2bf(float f) {  // RNE round to bf16
  unsigned u = __float_as_uint(f);
  return (u + 0x7FFFu + ((u >> 16) & 1u)) >> 16;
}

// ---------------------------------------------------------------------------
// Es0 = rs * concat(U,V) stored bf16 (pre-scaled S-space embeddings)
// ---------------------------------------------------------------------------
__global__ __launch_bounds__(256) void init_es_kernel(
    const float* __restrict__ U, const float* __restrict__ V,
    const float* __restrict__ rs, unsigned short* __restrict__ Es,
    int nU_elems, int total_elems) {
  int i4 = (blockIdx.x * blockDim.x + threadIdx.x) * 4;
  if (i4 >= total_elems) return;
  float4 v = (i4 < nU_elems)
      ? *reinterpret_cast<const float4*>(U + i4)
      : *reinterpret_cast<const float4*>(V + (i4 - nU_elems));
  float s = rs[i4 >> 6];
  uint2 o;
  o.x = f2bf(v.x * s) | (f2bf(v.y * s) << 16);
  o.y = f2bf(v.z * s) | (f2bf(v.w * s) << 16);
  *reinterpret_cast<uint2*>(Es + i4) = o;
}

// ---------------------------------------------------------------------------
// Pass A: LDS-staged multisplit of packed (row_low<<19 | col) 4B entries into
// fixed-capacity row-range buckets (base = b*BCAP).
// Flush quantum = 16 entries = one full 64B line at an aligned offset.
// Each block takes one chunk from the user half AND one from the item half of
// the half-range-split symmetric COO (threads 0..127 vs 128..255) so
// per-round bucket arrival stays ~5 << SCAP.
// ---------------------------------------------------------------------------
__global__ __launch_bounds__(PA_THREADS) void pass_a_kernel(
    const int* __restrict__ rows, const int* __restrict__ cols,
    unsigned* __restrict__ temp, int* __restrict__ gcur, int nnz, int nb) {
  __shared__ unsigned stage[NB_MAX * SPITCH];
  __shared__ int scnt[NB_MAX];
  for (int b = threadIdx.x; b < nb; b += PA_THREADS) scnt[b] = 0;
  __syncthreads();

  const int half = nnz >> 1;
  const int u0 = blockIdx.x * PA_HCHUNK;
  const int u1 = min(half, u0 + PA_HCHUNK);
  const int i0 = half + blockIdx.x * PA_HCHUNK;
  const int i1 = min(nnz, i0 + PA_HCHUNK);
  const int tid = threadIdx.x;

  for (int rd = 0; rd < PA_HCHUNK / PA_HALFROUND; ++rd) {
    int base, lim;
    if (tid < PA_THREADS / 2) {
      base = u0 + rd * PA_HALFROUND + tid * PA_K;
      lim = u1;
    } else {
      base = i0 + rd * PA_HALFROUND + (tid - PA_THREADS / 2) * PA_K;
      lim = i1;
    }

    unsigned packed[PA_K];
    int bkt[PA_K];
    unsigned pend = 0;  // bitmask of entries not yet staged
    if (base + PA_K <= lim && ((base & 3) == 0)) {
      int4 r4 = *reinterpret_cast<const int4*>(rows + base);
      int4 c4 = *reinterpret_cast<const int4*>(cols + base);
      int rr[PA_K] = {r4.x, r4.y, r4.z, r4.w};
      int cc[PA_K] = {c4.x, c4.y, c4.z, c4.w};
#pragma unroll
      for (int k = 0; k < PA_K; ++k) {
        bkt[k] = rr[k] >> BSHIFT;
        packed[k] = ((unsigned)(rr[k] & (BROWS - 1)) << 19) | (unsigned)cc[k];
      }
      pend = (1u << PA_K) - 1;
    } else {
#pragma unroll
      for (int k = 0; k < PA_K; ++k) {
        int e = base + k;
        if (e < lim) {
          int r = rows[e];
          int c = cols[e];
          bkt[k] = r >> BSHIFT;
          packed[k] = ((unsigned)(r & (BROWS - 1)) << 19) | (unsigned)c;
          pend |= 1u << k;
        }
      }
    }

    for (;;) {
#pragma unroll
      for (int k = 0; k < PA_K; ++k) {
        if (pend & (1u << k)) {
          int idx = atomicAdd(&scnt[bkt[k]], 1);
          if (idx < SCAP) {
            stage[bkt[k] * SPITCH + idx] = packed[k];
            pend &= ~(1u << k);
          } else {
            atomicAdd(&scnt[bkt[k]], -1);  // undo failed claim; retry after flush
          }
        }
      }
      __syncthreads();
      // flush full 16-groups (one thread per bucket, conflict-free pitch)
      for (int bb = threadIdx.x; bb < nb; bb += PA_THREADS) {
        int cval = scnt[bb];
        if (cval >= 16) {
          int pos = atomicAdd(&gcur[bb], 16);
          unsigned v[16];
#pragma unroll
          for (int k = 0; k < 16; ++k) v[k] = stage[bb * SPITCH + k];
          uint4* dst = reinterpret_cast<uint4*>(&temp[pos]);
          dst[0] = make_uint4(v[0], v[1], v[2], v[3]);
          dst[1] = make_uint4(v[4], v[5], v[6], v[7]);
          dst[2] = make_uint4(v[8], v[9], v[10], v[11]);
          dst[3] = make_uint4(v[12], v[13], v[14], v[15]);
          for (int k = 0; k < cval - 16; ++k)
            stage[bb * SPITCH + k] = stage[bb * SPITCH + 16 + k];
          scnt[bb] = cval - 16;
        }
      }
      int pend_total = __syncthreads_count(pend ? 1 : 0);
      if (pend_total == 0) break;
    }
  }
  // final drain: pad residue to a full aligned 16-group with sentinels
  __syncthreads();
  for (int bb = threadIdx.x; bb < nb; bb += PA_THREADS) {
    int cval = scnt[bb];
    if (cval > 0) {
      int pos = atomicAdd(&gcur[bb], 16);
      for (int k = 0; k < 16; ++k)
        temp[pos + k] = (k < cval) ? stage[bb * SPITCH + k] : SENTINEL;
    }
  }
}

// ---------------------------------------------------------------------------
// Per-bucket histogram: LDS atomics + coalesced contiguous cnt stores.
// ---------------------------------------------------------------------------
__global__ __launch_bounds__(512) void hist_bucket_kernel(
    const unsigned* __restrict__ temp, const int* __restrict__ gcur,
    int* __restrict__ cnt, int n) {
  __shared__ int lcnt[BROWS];
  int b = blockIdx.x;
  int base_row = b << BSHIFT;
  int nrows = min(BROWS, n - base_row);
  for (int r = threadIdx.x; r < BROWS; r += 512) lcnt[r] = 0;
  __syncthreads();
  int start = b * BCAP, end = gcur[b];
  for (int i = start + threadIdx.x; i < end; i += 512) {
    unsigned ent = temp[i];
    if (ent != SENTINEL) atomicAdd(&lcnt[ent >> 19], 1);
  }
  __syncthreads();
  for (int r = threadIdx.x; r < nrows; r += 512)
    cnt[base_row + r] = lcnt[r];
}

// phase1: per-block chunk reduction
__global__ __launch_bounds__(256) void scan_phase1(
    const int* __restrict__ cnt, int* __restrict__ block_sums, int n) {
  __shared__ int sdata[256];
  int base = blockIdx.x * SCAN_CHUNK;
  int sum = 0;
#pragma unroll
  for (int k = 0; k < 8; ++k) {
    int idx = base + k * 256 + threadIdx.x;
    if (idx < n) sum += cnt[idx];
  }
  sdata[threadIdx.x] = sum;
  __syncthreads();
  for (int s = 128; s > 0; s >>= 1) {
    if (threadIdx.x < s) sdata[threadIdx.x] += sdata[threadIdx.x + s];
    __syncthreads();
  }
  if (threadIdx.x == 0) block_sums[blockIdx.x] = sdata[0];
}

// phase2: single 256-wide exclusive scan over block sums; writes row_ptr[n]
__global__ __launch_bounds__(256) void scan_phase2(
    int* __restrict__ block_sums, int n_blocks, int* __restrict__ row_ptr, int n) {
  __shared__ int tmp[256];
  int v = (threadIdx.x < n_blocks) ? block_sums[threadIdx.x] : 0;
  tmp[threadIdx.x] = v;
  __syncthreads();
  for (int offs = 1; offs < 256; offs <<= 1) {
    int t = (threadIdx.x >= offs) ? tmp[threadIdx.x - offs] : 0;
    __syncthreads();
    tmp[threadIdx.x] += t;
    __syncthreads();
  }
  if (threadIdx.x < n_blocks) block_sums[threadIdx.x] = tmp[threadIdx.x] - v;
  if (threadIdx.x == 0) row_ptr[n] = tmp[255];
}

// phase3: per-block chunk scan with offset, writes row_ptr
__global__ __launch_bounds__(256) void scan_phase3(
    const int* __restrict__ cnt, const int* __restrict__ block_sums,
    int* __restrict__ row_ptr, int n) {
  __shared__ int tmp[256];
  __shared__ int s_carry;
  int base = blockIdx.x * SCAN_CHUNK;
  if (threadIdx.x == 0) s_carry = block_sums[blockIdx.x];
  __syncthreads();
#pragma unroll 1
  for (int k = 0; k < 8; ++k) {
    int idx = base + k * 256 + threadIdx.x;
    int v = (idx < n) ? cnt[idx] : 0;
    tmp[threadIdx.x] = v;
    __syncthreads();
    for (int offs = 1; offs < 256; offs <<= 1) {
      int t = (threadIdx.x >= offs) ? tmp[threadIdx.x - offs] : 0;
      __syncthreads();
      tmp[threadIdx.x] += t;
      __syncthreads();
    }
    int incl = tmp[threadIdx.x];
    int carry = s_carry;
    if (idx < n) row_ptr[idx] = carry + incl - v;
    __syncthreads();
    if (threadIdx.x == 0) s_carry = carry + tmp[255];
    __syncthreads();
  }
}

// rs = 1/sqrt(deg); rs2 = rs*rs (output scale); irs = sqrt(deg) (unscale)
__global__ __launch_bounds__(256) void rs_kernel(
    const int* __restrict__ cnt, float* __restrict__ rs,
    float* __restrict__ rs2, float* __restrict__ irs, int n) {
  int i = blockIdx.x * blockDim.x + threadIdx.x;
  if (i < n) {
    float d = (float)cnt[i];
    float r = (d > 0.0f) ? 1.0f / sqrtf(d) : 1.0f;
    rs[i] = r;
    rs2[i] = r * r;
    irs[i] = (d > 0.0f) ? sqrtf(d) : 1.0f;
  }
}

// gcur init for fixed-capacity buckets
__global__ __launch_bounds__(256) void bucket_init_kernel(
    int* __restrict__ gcur, int nb) {
  int b = blockIdx.x * blockDim.x + threadIdx.x;
  if (b < nb) gcur[b] = b * BCAP;
}

// ---------------------------------------------------------------------------
// Pass B: per bucket, scatter bucket entries to exact CSR positions.
// S-space iteration needs no per-edge value: CSR payload is just the col id.
// One bucket per block (grid = NB).
// ---------------------------------------------------------------------------
__global__ __launch_bounds__(PB_THREADS) void pass_b_kernel(
    const unsigned* __restrict__ temp, const int* __restrict__ gcur,
    const int* __restrict__ row_ptr, int* __restrict__ csr_col, int nb, int n) {
  __shared__ int ldscur[BROWS];
  for (int b = blockIdx.x; b < nb; b += gridDim.x) {
    int base_row = b << BSHIFT;
    int nrows = min(BROWS, n - base_row);
    for (int r = threadIdx.x; r < nrows; r += PB_THREADS)
      ldscur[r] = row_ptr[base_row + r];
    __syncthreads();
    int start = b * BCAP, end = gcur[b];
    for (int i = start + threadIdx.x; i < end; i += PB_THREADS) {
      unsigned ent = temp[i];
      if (ent != SENTINEL) {
        int col = (int)(ent & 0x7FFFFu);
        int rlow = (int)(ent >> 19);
        int p = atomicAdd(&ldscur[rlow], 1);
        csr_col[p] = col;
      }
    }
    __syncthreads();
  }
}

// ---------------------------------------------------------------------------
// SpMM in S-space, bf16 storage: one wave per row; the wave's four 16-lane
// quarters each gather a different edge's bf16 row as 8B. Single fully-
// predicated 16-edge loop: every iteration keeps 4 gathers in flight, OOR
// edges clamp to end-1 (L1-hit duplicate) and are zeroed by cndmask -- no
// 1-deep tail loop (mean item degree ~25 lives in the tail otherwise).
// acc in fp32; epilogue applies rs2[row], packs bf16; quarter 0 stores 128B.
// ---------------------------------------------------------------------------
__global__ __launch_bounds__(256) void spmm_kernel(
    const int* __restrict__ row_ptr, const int* __restrict__ csr_col,
    const float* __restrict__ rs2, const uint2* __restrict__ cur2,
    uint2* __restrict__ next2, int n_rows) {
  int row  = blockIdx.x * (blockDim.x >> 6) + (threadIdx.x >> 6);
  int lane = threadIdx.x & 63;
  int q    = lane >> 4;   // quarter: which edge of the group of 4
  int sub  = lane & 15;   // 8B chunk (4 bf16 dims) within the gathered row
  if (row >= n_rows) return;
  int start = row_ptr[row];
  int end   = row_ptr[row + 1];
  float4 acc = make_float4(0.0f, 0.0f, 0.0f, 0.0f);
  for (int e = start; e < end; e += 16) {
    int c[4];
    bool m[4];
    uint2 g[4];
#pragma unroll
    for (int k = 0; k < 4; ++k) {
      int idx = e + 4 * k + q;
      m[k] = idx < end;
      c[k] = ld_nt_int(csr_col + (m[k] ? idx : (end - 1)));
    }
#pragma unroll
    for (int k = 0; k < 4; ++k) g[k] = cur2[c[k] * 16 + sub];
#pragma unroll
    for (int k = 0; k < 4; ++k) {
      unsigned gx = m[k] ? g[k].x : 0u;
      unsigned gy = m[k] ? g[k].y : 0u;
      acc.x += bf_lo(gx); acc.y += bf_hi(gx);
      acc.z += bf_lo(gy); acc.w += bf_hi(gy);
    }
  }
  // combine the four quarter partial sums
#pragma unroll
  for (int offs = 16; offs <= 32; offs <<= 1) {
    acc.x += __shfl_xor(acc.x, offs, 64);
    acc.y += __shfl_xor(acc.y, offs, 64);
    acc.z += __shfl_xor(acc.z, offs, 64);
    acc.w += __shfl_xor(acc.w, offs, 64);
  }
  if (q == 0) {
    float s = rs2[row];
    uint2 o;
    o.x = f2bf(acc.x * s) | (f2bf(acc.y * s) << 16);
    o.y = f2bf(acc.z * s) | (f2bf(acc.w * s) << 16);
    next2[row * 16 + sub] = o;
  }
}

// ---------------------------------------------------------------------------
// Layer-3 batch-restricted SpMM: only the 2*batch rows needed by the output.
// acc[b] += rs[row] * sum_{c in N(row)} S2[c]   (== gather(E3) exactly)
// One wave per (batch-slot, side) task; same predicated quarter-gather loop.
// ---------------------------------------------------------------------------
__global__ __launch_bounds__(256) void batch_spmm_kernel(
    const int* __restrict__ u, const int* __restrict__ it,
    const int* __restrict__ row_ptr, const int* __restrict__ csr_col,
    const float* __restrict__ rs, const uint2* __restrict__ cur2,
    float* __restrict__ accU, float* __restrict__ accI, int batch, int nU) {
  int t    = blockIdx.x * (blockDim.x >> 6) + (threadIdx.x >> 6);
  int lane = threadIdx.x & 63;
  int q    = lane >> 4;
  int sub  = lane & 15;
  if (t >= 2 * batch) return;
  int b = t >> 1;
  bool uside = (t & 1) == 0;
  int row = uside ? u[b] : (it[b] + nU);
  int start = row_ptr[row];
  int end   = row_ptr[row + 1];
  float4 acc = make_float4(0.0f, 0.0f, 0.0f, 0.0f);
  for (int e = start; e < end; e += 16) {
    int c[4];
    bool m[4];
    uint2 g[4];
#pragma unroll
    for (int k = 0; k < 4; ++k) {
      int idx = e + 4 * k + q;
      m[k] = idx < end;
      c[k] = ld_nt_int(csr_col + (m[k] ? idx : (end - 1)));
    }
#pragma unroll
    for (int k = 0; k < 4; ++k) g[k] = cur2[c[k] * 16 + sub];
#pragma unroll
    for (int k = 0; k < 4; ++k) {
      unsigned gx = m[k] ? g[k].x : 0u;
      unsigned gy = m[k] ? g[k].y : 0u;
      acc.x += bf_lo(gx); acc.y += bf_hi(gx);
      acc.z += bf_lo(gy); acc.w += bf_hi(gy);
    }
  }
#pragma unroll
  for (int offs = 16; offs <= 32; offs <<= 1) {
    acc.x += __shfl_xor(acc.x, offs, 64);
    acc.y += __shfl_xor(acc.y, offs, 64);
    acc.z += __shfl_xor(acc.z, offs, 64);
    acc.w += __shfl_xor(acc.w, offs, 64);
  }
  if (q == 0) {
    float s = rs[row];
    float* dst = (uside ? accU : accI) + (size_t)b * DIMS + sub * 4;
    float4 old = *reinterpret_cast<float4*>(dst);
    old.x += acc.x * s; old.y += acc.y * s;
    old.z += acc.z * s; old.w += acc.w * s;
    *reinterpret_cast<float4*>(dst) = old;
  }
}

// ---------------------------------------------------------------------------
// Layer-0 batch gather: exact fp32 E0 rows straight from U/V (initializes acc)
// ---------------------------------------------------------------------------
__global__ __launch_bounds__(256) void gather0_kernel(
    const int* __restrict__ u, const int* __restrict__ it,
    const float* __restrict__ U, const float* __restrict__ V,
    float* __restrict__ accU, float* __restrict__ accI, int batch) {
  int b    = blockIdx.x * (blockDim.x >> 6) + (threadIdx.x >> 6);
  int lane = threadIdx.x & 63;
  if (b >= batch) return;
  accU[b * DIMS + lane] = U[u[b] * DIMS + lane];
  accI[b * DIMS + lane] = V[it[b] * DIMS + lane];
}

// Layer-k batch gather from S-space bf16: unscale by irs = sqrt(deg)
__global__ __launch_bounds__(256) void gather_s_kernel(
    const int* __restrict__ u, const int* __restrict__ it,
    const unsigned short* __restrict__ curS, const float* __restrict__ irs,
    float* __restrict__ accU, float* __restrict__ accI, int batch, int nU) {
  int b    = blockIdx.x * (blockDim.x >> 6) + (threadIdx.x >> 6);
  int lane = threadIdx.x & 63;
  if (b >= batch) return;
  int ru = u[b];
  int ri = it[b] + nU;
  accU[b * DIMS + lane] +=
      __uint_as_float((unsigned)curS[ru * DIMS + lane] << 16) * irs[ru];
  accI[b * DIMS + lane] +=
      __uint_as_float((unsigned)curS[ri * DIMS + lane] << 16) * irs[ri];
}

__global__ __launch_bounds__(256) void score_kernel(
    const float* __restrict__ accU, const float* __restrict__ accI,
    float* __restrict__ out, int batch) {
  int b    = blockIdx.x * (blockDim.x >> 6) + (threadIdx.x >> 6);
  int lane = threadIdx.x & 63;
  if (b >= batch) return;
  float v = accU[b * DIMS + lane] * accI[b * DIMS + lane];
  for (int offs = 32; offs > 0; offs >>= 1) v += __shfl_down(v, offs, 64);
  if (lane == 0) out[b] = v * (1.0f / 16.0f);
}

// ---------------------------------------------------------------------------
extern "C" void kernel_launch(void* const* d_in, const int* in_sizes, int n_in,
                              void* d_out, int out_size, void* d_ws, size_t ws_size,
                              hipStream_t stream) {
  const int*   u     = (const int*)d_in[0];
  const int*   it    = (const int*)d_in[1];
  const int*   arows = (const int*)d_in[2];
  const int*   acols = (const int*)d_in[3];
  const float* U     = (const float*)d_in[5];
  const float* V     = (const float*)d_in[6];

  const int batch = in_sizes[0];
  const int nnz   = in_sizes[2];
  const int nU    = in_sizes[5] / DIMS;
  const int nV    = in_sizes[6] / DIMS;
  const int N     = nU + nV;
  const int n_scan_blocks = (N + SCAN_CHUNK - 1) / SCAN_CHUNK;
  const int NB    = (N + BROWS - 1) >> BSHIFT;  // 293
  const size_t esbytes = (size_t)N * DIMS * 2;  // bf16 embeddings
  const size_t tbytes  = (size_t)NB * BCAP * 4;
  const size_t xbytes  = tbytes > esbytes ? tbytes : esbytes;

  // pass_a grid: each block covers one PA_HCHUNK chunk of EACH half
  const int big_half = nnz - nnz / 2;
  const int PA_B = (big_half + PA_HCHUNK - 1) / PA_HCHUNK;

  char*  ws  = (char*)d_ws;
  size_t off = 0;
  auto take = [&](size_t bytes) -> void* {
    void* p = ws + off;
    off = (off + bytes + 255) & ~(size_t)255;
    return p;
  };
  int*     cnt        = (int*)take((size_t)N * 4);
  float*   rs         = (float*)take((size_t)N * 4);
  float*   rs2        = (float*)take((size_t)N * 4);
  float*   irs        = (float*)take((size_t)N * 4);
  int*     row_ptr    = (int*)take((size_t)(N + 1) * 4);
  int*     block_sums = (int*)take((size_t)256 * 4);
  int*     gcur       = (int*)take((size_t)NB * 4);
  int*     csr_col    = (int*)take((size_t)nnz * 4);
  char*    X          = (char*)take(xbytes);   // temp (build), then bufA (Es)
  unsigned short* bufB = (unsigned short*)take(esbytes);
  float*   accU       = (float*)take((size_t)batch * DIMS * 4);
  float*   accI       = (float*)take((size_t)batch * DIMS * 4);
  unsigned* temp      = (unsigned*)X;
  unsigned short* bufA = (unsigned short*)X;

  // ---- CSR build (uses X as temp) ----
  bucket_init_kernel<<<(NB + 255) / 256, 256, 0, stream>>>(gcur, NB);
  pass_a_kernel<<<PA_B, PA_THREADS, 0, stream>>>(arows, acols, temp, gcur, nnz, NB);
  hist_bucket_kernel<<<NB, 512, 0, stream>>>(temp, gcur, cnt, N);
  scan_phase1<<<n_scan_blocks, 256, 0, stream>>>(cnt, block_sums, N);
  scan_phase2<<<1, 256, 0, stream>>>(block_sums, n_scan_blocks, row_ptr, N);
  scan_phase3<<<n_scan_blocks, 256, 0, stream>>>(cnt, block_sums, row_ptr, N);
  rs_kernel<<<(N + 255) / 256, 256, 0, stream>>>(cnt, rs, rs2, irs, N);
  pass_b_kernel<<<NB, PB_THREADS, 0, stream>>>(temp, gcur, row_ptr,
                                               csr_col, NB, N);

  // ---- batch acc init with exact fp32 E0 rows (no memset needed) ----
  gather0_kernel<<<(batch + 3) / 4, 256, 0, stream>>>(u, it, U, V, accU, accI,
                                                      batch);

  // ---- Es0 = rs * E0 in bf16 (X becomes bufA now that temp is dead) ----
  {
    int total = N * DIMS;
    int t4 = total / 4;
    init_es_kernel<<<(t4 + 255) / 256, 256, 0, stream>>>(U, V, rs, bufA,
                                                         nU * DIMS, total);
  }

  // ---- layers 1,2: full SpMM + batch gather; layer 3: batch-restricted ----
  unsigned short* cur = bufA;
  unsigned short* nxt = bufB;
  for (int layer = 0; layer < 2; ++layer) {
    spmm_kernel<<<(N + 3) / 4, 256, 0, stream>>>(
        row_ptr, csr_col, rs2, (const uint2*)cur, (uint2*)nxt, N);
    gather_s_kernel<<<(batch + 3) / 4, 256, 0, stream>>>(u, it, nxt, irs, accU,
                                                         accI, batch, nU);
    unsigned short* t = cur; cur = nxt; nxt = t;
  }
  batch_spmm_kernel<<<(2 * batch + 3) / 4, 256, 0, stream>>>(
      u, it, row_ptr, csr_col, rs, (const uint2*)cur, accU, accI, batch, nU);

  score_kernel<<<(batch + 3) / 4, 256, 0, stream>>>(accU, accI, (float*)d_out, batch);
}

// Round 5
// 857.531 us; speedup vs baseline: 2.0900x; 1.0764x over previous
//
#include <hip/hip_runtime.h>

#define DIMS 64
#define SCAN_CHUNK 2048  // 256 threads * 8 elems
#define BSHIFT 10        // 1024 rows per bucket
#define BROWS (1 << BSHIFT)
#define NB_MAX 304       // >= ceil(300K/1024)=293
#define BCAP 65536       // fixed bucket capacity (mean ~34K + drain pads <54K)
#define SCAP 40          // staged entries per bucket (mirror staging doubles arrival)
#define SPITCH 41        // odd pitch -> bank-conflict-free across buckets
#define PA_THREADS 256
#define PA_K 4           // edge-PAIRS per thread per round (int4 vector loads)
#define PA_ROUND (PA_THREADS * PA_K)  // 1024 pairs -> 2048 staged entries/round
#define PA_CHUNK 4096    // edge-pairs per block (4 rounds)
#define PB_THREADS 512
#define SENTINEL 0xFFFFFFFFu

// nt 4B load (edge col stream): keep the 40MB/layer CSR stream from
// polluting L2, which stays dedicated to the hot 38MB bf16 gather target
__device__ __forceinline__ int ld_nt_int(const int* p) {
  return __builtin_nontemporal_load(p);
}

// bf16 <-> f32 helpers (storage-only bf16; all math in fp32)
__device__ __forceinline__ float bf_lo(unsigned u) {
  return __uint_as_float(u << 16);
}
__device__ __forceinline__ float bf_hi(unsigned u) {
  return __uint_as_float(u & 0xFFFF0000u);
}
__device__ __forceinline__ unsigned f2bf(float f) {  // RNE round to bf16
  unsigned u = __float_as_uint(f);
  return (u + 0x7FFFu + ((u >> 16) & 1u)) >> 16;
}

// ---------------------------------------------------------------------------
// Es0 = rs * concat(U,V) stored bf16 (pre-scaled S-space embeddings)
// ---------------------------------------------------------------------------
__global__ __launch_bounds__(256) void init_es_kernel(
    const float* __restrict__ U, const float* __restrict__ V,
    const float* __restrict__ rs, unsigned short* __restrict__ Es,
    int nU_elems, int total_elems) {
  int i4 = (blockIdx.x * blockDim.x + threadIdx.x) * 4;
  if (i4 >= total_elems) return;
  float4 v = (i4 < nU_elems)
      ? *reinterpret_cast<const float4*>(U + i4)
      : *reinterpret_cast<const float4*>(V + (i4 - nU_elems));
  float s = rs[i4 >> 6];
  uint2 o;
  o.x = f2bf(v.x * s) | (f2bf(v.y * s) << 16);
  o.y = f2bf(v.z * s) | (f2bf(v.w * s) << 16);
  *reinterpret_cast<uint2*>(Es + i4) = o;
}

// ---------------------------------------------------------------------------
// Pass A: LDS-staged multisplit of packed (row_low<<19 | col) 4B entries into
// fixed-capacity row-range buckets (base = b*BCAP).
// Mirror staging: the symmetric COO's second half is exactly the mirror of
// the first (rows=concat[uu,ii], cols=concat[ii,uu]), so each thread loads
// only first-half (u,i) pairs and stages BOTH orientations -- same staged
// multiset, half the rounds, half the load-latency exposure.
// Flush quantum = 16 entries = one full 64B line at an aligned offset;
// flush fully drains (while >=16) so residue stays <16 with SCAP=40.
// ---------------------------------------------------------------------------
__global__ __launch_bounds__(PA_THREADS) void pass_a_kernel(
    const int* __restrict__ rows, const int* __restrict__ cols,
    unsigned* __restrict__ temp, int* __restrict__ gcur, int nnz, int nb) {
  __shared__ unsigned stage[NB_MAX * SPITCH];
  __shared__ int scnt[NB_MAX];
  for (int b = threadIdx.x; b < nb; b += PA_THREADS) scnt[b] = 0;
  __syncthreads();

  const int half = nnz >> 1;
  const int c0 = blockIdx.x * PA_CHUNK;
  const int c1 = min(half, c0 + PA_CHUNK);

  for (int rd = 0; rd < PA_CHUNK / PA_ROUND; ++rd) {
    int base = c0 + rd * PA_ROUND + threadIdx.x * PA_K;

    unsigned packed[2 * PA_K];
    int bkt[2 * PA_K];
    unsigned pend = 0;  // bitmask of entries not yet staged
    if (base + PA_K <= c1) {  // base is always 16B-aligned by construction
      int4 r4 = *reinterpret_cast<const int4*>(rows + base);
      int4 c4 = *reinterpret_cast<const int4*>(cols + base);
      int rr[PA_K] = {r4.x, r4.y, r4.z, r4.w};
      int cc[PA_K] = {c4.x, c4.y, c4.z, c4.w};
#pragma unroll
      for (int k = 0; k < PA_K; ++k) {
        bkt[2 * k] = rr[k] >> BSHIFT;
        packed[2 * k] =
            ((unsigned)(rr[k] & (BROWS - 1)) << 19) | (unsigned)cc[k];
        bkt[2 * k + 1] = cc[k] >> BSHIFT;
        packed[2 * k + 1] =
            ((unsigned)(cc[k] & (BROWS - 1)) << 19) | (unsigned)rr[k];
      }
      pend = (1u << (2 * PA_K)) - 1;
    } else {
#pragma unroll
      for (int k = 0; k < PA_K; ++k) {
        int e = base + k;
        if (e < c1) {
          int r = rows[e];
          int c = cols[e];
          bkt[2 * k] = r >> BSHIFT;
          packed[2 * k] = ((unsigned)(r & (BROWS - 1)) << 19) | (unsigned)c;
          bkt[2 * k + 1] = c >> BSHIFT;
          packed[2 * k + 1] = ((unsigned)(c & (BROWS - 1)) << 19) | (unsigned)r;
          pend |= 3u << (2 * k);
        }
      }
    }

    for (;;) {
#pragma unroll
      for (int k = 0; k < 2 * PA_K; ++k) {
        if (pend & (1u << k)) {
          int idx = atomicAdd(&scnt[bkt[k]], 1);
          if (idx < SCAP) {
            stage[bkt[k] * SPITCH + idx] = packed[k];
            pend &= ~(1u << k);
          } else {
            atomicAdd(&scnt[bkt[k]], -1);  // undo failed claim; retry after flush
          }
        }
      }
      __syncthreads();
      // flush ALL full 16-groups (one thread per bucket, conflict-free pitch)
      for (int bb = threadIdx.x; bb < nb; bb += PA_THREADS) {
        int cval = scnt[bb];
        if (cval >= 16) {
          while (cval >= 16) {
            int pos = atomicAdd(&gcur[bb], 16);
            unsigned v[16];
#pragma unroll
            for (int k = 0; k < 16; ++k) v[k] = stage[bb * SPITCH + k];
            uint4* dst = reinterpret_cast<uint4*>(&temp[pos]);
            dst[0] = make_uint4(v[0], v[1], v[2], v[3]);
            dst[1] = make_uint4(v[4], v[5], v[6], v[7]);
            dst[2] = make_uint4(v[8], v[9], v[10], v[11]);
            dst[3] = make_uint4(v[12], v[13], v[14], v[15]);
            for (int k = 0; k < cval - 16; ++k)
              stage[bb * SPITCH + k] = stage[bb * SPITCH + 16 + k];
            cval -= 16;
          }
          scnt[bb] = cval;
        }
      }
      int pend_total = __syncthreads_count(pend ? 1 : 0);
      if (pend_total == 0) break;
    }
  }
  // final drain: pad residue to a full aligned 16-group with sentinels
  __syncthreads();
  for (int bb = threadIdx.x; bb < nb; bb += PA_THREADS) {
    int cval = scnt[bb];
    if (cval > 0) {
      int pos = atomicAdd(&gcur[bb], 16);
      for (int k = 0; k < 16; ++k)
        temp[pos + k] = (k < cval) ? stage[bb * SPITCH + k] : SENTINEL;
    }
  }
}

// ---------------------------------------------------------------------------
// Per-bucket histogram: LDS atomics + coalesced contiguous cnt stores.
// ---------------------------------------------------------------------------
__global__ __launch_bounds__(512) void hist_bucket_kernel(
    const unsigned* __restrict__ temp, const int* __restrict__ gcur,
    int* __restrict__ cnt, int n) {
  __shared__ int lcnt[BROWS];
  int b = blockIdx.x;
  int base_row = b << BSHIFT;
  int nrows = min(BROWS, n - base_row);
  for (int r = threadIdx.x; r < BROWS; r += 512) lcnt[r] = 0;
  __syncthreads();
  int start = b * BCAP, end = gcur[b];
  for (int i = start + threadIdx.x; i < end; i += 512) {
    unsigned ent = temp[i];
    if (ent != SENTINEL) atomicAdd(&lcnt[ent >> 19], 1);
  }
  __syncthreads();
  for (int r = threadIdx.x; r < nrows; r += 512)
    cnt[base_row + r] = lcnt[r];
}

// phase1: per-block chunk reduction
__global__ __launch_bounds__(256) void scan_phase1(
    const int* __restrict__ cnt, int* __restrict__ block_sums, int n) {
  __shared__ int sdata[256];
  int base = blockIdx.x * SCAN_CHUNK;
  int sum = 0;
#pragma unroll
  for (int k = 0; k < 8; ++k) {
    int idx = base + k * 256 + threadIdx.x;
    if (idx < n) sum += cnt[idx];
  }
  sdata[threadIdx.x] = sum;
  __syncthreads();
  for (int s = 128; s > 0; s >>= 1) {
    if (threadIdx.x < s) sdata[threadIdx.x] += sdata[threadIdx.x + s];
    __syncthreads();
  }
  if (threadIdx.x == 0) block_sums[blockIdx.x] = sdata[0];
}

// phase2: single 256-wide exclusive scan over block sums; writes row_ptr[n]
__global__ __launch_bounds__(256) void scan_phase2(
    int* __restrict__ block_sums, int n_blocks, int* __restrict__ row_ptr, int n) {
  __shared__ int tmp[256];
  int v = (threadIdx.x < n_blocks) ? block_sums[threadIdx.x] : 0;
  tmp[threadIdx.x] = v;
  __syncthreads();
  for (int offs = 1; offs < 256; offs <<= 1) {
    int t = (threadIdx.x >= offs) ? tmp[threadIdx.x - offs] : 0;
    __syncthreads();
    tmp[threadIdx.x] += t;
    __syncthreads();
  }
  if (threadIdx.x < n_blocks) block_sums[threadIdx.x] = tmp[threadIdx.x] - v;
  if (threadIdx.x == 0) row_ptr[n] = tmp[255];
}

// phase3: per-block chunk scan with offset, writes row_ptr
__global__ __launch_bounds__(256) void scan_phase3(
    const int* __restrict__ cnt, const int* __restrict__ block_sums,
    int* __restrict__ row_ptr, int n) {
  __shared__ int tmp[256];
  __shared__ int s_carry;
  int base = blockIdx.x * SCAN_CHUNK;
  if (threadIdx.x == 0) s_carry = block_sums[blockIdx.x];
  __syncthreads();
#pragma unroll 1
  for (int k = 0; k < 8; ++k) {
    int idx = base + k * 256 + threadIdx.x;
    int v = (idx < n) ? cnt[idx] : 0;
    tmp[threadIdx.x] = v;
    __syncthreads();
    for (int offs = 1; offs < 256; offs <<= 1) {
      int t = (threadIdx.x >= offs) ? tmp[threadIdx.x - offs] : 0;
      __syncthreads();
      tmp[threadIdx.x] += t;
      __syncthreads();
    }
    int incl = tmp[threadIdx.x];
    int carry = s_carry;
    if (idx < n) row_ptr[idx] = carry + incl - v;
    __syncthreads();
    if (threadIdx.x == 0) s_carry = carry + tmp[255];
    __syncthreads();
  }
}

// rs = 1/sqrt(deg); rs2 = rs*rs (output scale); irs = sqrt(deg) (unscale)
__global__ __launch_bounds__(256) void rs_kernel(
    const int* __restrict__ cnt, float* __restrict__ rs,
    float* __restrict__ rs2, float* __restrict__ irs, int n) {
  int i = blockIdx.x * blockDim.x + threadIdx.x;
  if (i < n) {
    float d = (float)cnt[i];
    float r = (d > 0.0f) ? 1.0f / sqrtf(d) : 1.0f;
    rs[i] = r;
    rs2[i] = r * r;
    irs[i] = (d > 0.0f) ? sqrtf(d) : 1.0f;
  }
}

// gcur init for fixed-capacity buckets
__global__ __launch_bounds__(256) void bucket_init_kernel(
    int* __restrict__ gcur, int nb) {
  int b = blockIdx.x * blockDim.x + threadIdx.x;
  if (b < nb) gcur[b] = b * BCAP;
}

// ---------------------------------------------------------------------------
// Pass B: per bucket, scatter bucket entries to exact CSR positions.
// S-space iteration needs no per-edge value: CSR payload is just the col id.
// One bucket per block (grid = NB).
// ---------------------------------------------------------------------------
__global__ __launch_bounds__(PB_THREADS) void pass_b_kernel(
    const unsigned* __restrict__ temp, const int* __restrict__ gcur,
    const int* __restrict__ row_ptr, int* __restrict__ csr_col, int nb, int n) {
  __shared__ int ldscur[BROWS];
  for (int b = blockIdx.x; b < nb; b += gridDim.x) {
    int base_row = b << BSHIFT;
    int nrows = min(BROWS, n - base_row);
    for (int r = threadIdx.x; r < nrows; r += PB_THREADS)
      ldscur[r] = row_ptr[base_row + r];
    __syncthreads();
    int start = b * BCAP, end = gcur[b];
    for (int i = start + threadIdx.x; i < end; i += PB_THREADS) {
      unsigned ent = temp[i];
      if (ent != SENTINEL) {
        int col = (int)(ent & 0x7FFFFu);
        int rlow = (int)(ent >> 19);
        int p = atomicAdd(&ldscur[rlow], 1);
        csr_col[p] = col;
      }
    }
    __syncthreads();
  }
}

// ---------------------------------------------------------------------------
// SpMM in S-space, bf16 storage: one wave per row; the wave's four 16-lane
// quarters each gather a different edge's bf16 row as 8B. Single fully-
// predicated 16-edge loop: every iteration keeps 4 gathers in flight, OOR
// edges clamp to end-1 (L1-hit duplicate) and are zeroed by cndmask -- no
// 1-deep tail loop (mean item degree ~25 lives in the tail otherwise).
// acc in fp32; epilogue applies rs2[row], packs bf16; quarter 0 stores 128B.
// ---------------------------------------------------------------------------
__global__ __launch_bounds__(256) void spmm_kernel(
    const int* __restrict__ row_ptr, const int* __restrict__ csr_col,
    const float* __restrict__ rs2, const uint2* __restrict__ cur2,
    uint2* __restrict__ next2, int n_rows) {
  int row  = blockIdx.x * (blockDim.x >> 6) + (threadIdx.x >> 6);
  int lane = threadIdx.x & 63;
  int q    = lane >> 4;   // quarter: which edge of the group of 4
  int sub  = lane & 15;   // 8B chunk (4 bf16 dims) within the gathered row
  if (row >= n_rows) return;
  int start = row_ptr[row];
  int end   = row_ptr[row + 1];
  float4 acc = make_float4(0.0f, 0.0f, 0.0f, 0.0f);
  for (int e = start; e < end; e += 16) {
    int c[4];
    bool m[4];
    uint2 g[4];
#pragma unroll
    for (int k = 0; k < 4; ++k) {
      int idx = e + 4 * k + q;
      m[k] = idx < end;
      c[k] = ld_nt_int(csr_col + (m[k] ? idx : (end - 1)));
    }
#pragma unroll
    for (int k = 0; k < 4; ++k) g[k] = cur2[c[k] * 16 + sub];
#pragma unroll
    for (int k = 0; k < 4; ++k) {
      unsigned gx = m[k] ? g[k].x : 0u;
      unsigned gy = m[k] ? g[k].y : 0u;
      acc.x += bf_lo(gx); acc.y += bf_hi(gx);
      acc.z += bf_lo(gy); acc.w += bf_hi(gy);
    }
  }
  // combine the four quarter partial sums
#pragma unroll
  for (int offs = 16; offs <= 32; offs <<= 1) {
    acc.x += __shfl_xor(acc.x, offs, 64);
    acc.y += __shfl_xor(acc.y, offs, 64);
    acc.z += __shfl_xor(acc.z, offs, 64);
    acc.w += __shfl_xor(acc.w, offs, 64);
  }
  if (q == 0) {
    float s = rs2[row];
    uint2 o;
    o.x = f2bf(acc.x * s) | (f2bf(acc.y * s) << 16);
    o.y = f2bf(acc.z * s) | (f2bf(acc.w * s) << 16);
    next2[row * 16 + sub] = o;
  }
}

// ---------------------------------------------------------------------------
// Layer-3 batch-restricted SpMM: only the 2*batch rows needed by the output.
// acc[b] += rs[row] * sum_{c in N(row)} S2[c]   (== gather(E3) exactly)
// One wave per (batch-slot, side) task; same predicated quarter-gather loop.
// ---------------------------------------------------------------------------
__global__ __launch_bounds__(256) void batch_spmm_kernel(
    const int* __restrict__ u, const int* __restrict__ it,
    const int* __restrict__ row_ptr, const int* __restrict__ csr_col,
    const float* __restrict__ rs, const uint2* __restrict__ cur2,
    float* __restrict__ accU, float* __restrict__ accI, int batch, int nU) {
  int t    = blockIdx.x * (blockDim.x >> 6) + (threadIdx.x >> 6);
  int lane = threadIdx.x & 63;
  int q    = lane >> 4;
  int sub  = lane & 15;
  if (t >= 2 * batch) return;
  int b = t >> 1;
  bool uside = (t & 1) == 0;
  int row = uside ? u[b] : (it[b] + nU);
  int start = row_ptr[row];
  int end   = row_ptr[row + 1];
  float4 acc = make_float4(0.0f, 0.0f, 0.0f, 0.0f);
  for (int e = start; e < end; e += 16) {
    int c[4];
    bool m[4];
    uint2 g[4];
#pragma unroll
    for (int k = 0; k < 4; ++k) {
      int idx = e + 4 * k + q;
      m[k] = idx < end;
      c[k] = ld_nt_int(csr_col + (m[k] ? idx : (end - 1)));
    }
#pragma unroll
    for (int k = 0; k < 4; ++k) g[k] = cur2[c[k] * 16 + sub];
#pragma unroll
    for (int k = 0; k < 4; ++k) {
      unsigned gx = m[k] ? g[k].x : 0u;
      unsigned gy = m[k] ? g[k].y : 0u;
      acc.x += bf_lo(gx); acc.y += bf_hi(gx);
      acc.z += bf_lo(gy); acc.w += bf_hi(gy);
    }
  }
#pragma unroll
  for (int offs = 16; offs <= 32; offs <<= 1) {
    acc.x += __shfl_xor(acc.x, offs, 64);
    acc.y += __shfl_xor(acc.y, offs, 64);
    acc.z += __shfl_xor(acc.z, offs, 64);
    acc.w += __shfl_xor(acc.w, offs, 64);
  }
  if (q == 0) {
    float s = rs[row];
    float* dst = (uside ? accU : accI) + (size_t)b * DIMS + sub * 4;
    float4 old = *reinterpret_cast<float4*>(dst);
    old.x += acc.x * s; old.y += acc.y * s;
    old.z += acc.z * s; old.w += acc.w * s;
    *reinterpret_cast<float4*>(dst) = old;
  }
}

// ---------------------------------------------------------------------------
// Layer-0 batch gather: exact fp32 E0 rows straight from U/V (initializes acc)
// ---------------------------------------------------------------------------
__global__ __launch_bounds__(256) void gather0_kernel(
    const int* __restrict__ u, const int* __restrict__ it,
    const float* __restrict__ U, const float* __restrict__ V,
    float* __restrict__ accU, float* __restrict__ accI, int batch) {
  int b    = blockIdx.x * (blockDim.x >> 6) + (threadIdx.x >> 6);
  int lane = threadIdx.x & 63;
  if (b >= batch) return;
  accU[b * DIMS + lane] = U[u[b] * DIMS + lane];
  accI[b * DIMS + lane] = V[it[b] * DIMS + lane];
}

// Layer-k batch gather from S-space bf16: unscale by irs = sqrt(deg)
__global__ __launch_bounds__(256) void gather_s_kernel(
    const int* __restrict__ u, const int* __restrict__ it,
    const unsigned short* __restrict__ curS, const float* __restrict__ irs,
    float* __restrict__ accU, float* __restrict__ accI, int batch, int nU) {
  int b    = blockIdx.x * (blockDim.x >> 6) + (threadIdx.x >> 6);
  int lane = threadIdx.x & 63;
  if (b >= batch) return;
  int ru = u[b];
  int ri = it[b] + nU;
  accU[b * DIMS + lane] +=
      __uint_as_float((unsigned)curS[ru * DIMS + lane] << 16) * irs[ru];
  accI[b * DIMS + lane] +=
      __uint_as_float((unsigned)curS[ri * DIMS + lane] << 16) * irs[ri];
}

__global__ __launch_bounds__(256) void score_kernel(
    const float* __restrict__ accU, const float* __restrict__ accI,
    float* __restrict__ out, int batch) {
  int b    = blockIdx.x * (blockDim.x >> 6) + (threadIdx.x >> 6);
  int lane = threadIdx.x & 63;
  if (b >= batch) return;
  float v = accU[b * DIMS + lane] * accI[b * DIMS + lane];
  for (int offs = 32; offs > 0; offs >>= 1) v += __shfl_down(v, offs, 64);
  if (lane == 0) out[b] = v * (1.0f / 16.0f);
}

// ---------------------------------------------------------------------------
extern "C" void kernel_launch(void* const* d_in, const int* in_sizes, int n_in,
                              void* d_out, int out_size, void* d_ws, size_t ws_size,
                              hipStream_t stream) {
  const int*   u     = (const int*)d_in[0];
  const int*   it    = (const int*)d_in[1];
  const int*   arows = (const int*)d_in[2];
  const int*   acols = (const int*)d_in[3];
  const float* U     = (const float*)d_in[5];
  const float* V     = (const float*)d_in[6];

  const int batch = in_sizes[0];
  const int nnz   = in_sizes[2];
  const int nU    = in_sizes[5] / DIMS;
  const int nV    = in_sizes[6] / DIMS;
  const int N     = nU + nV;
  const int n_scan_blocks = (N + SCAN_CHUNK - 1) / SCAN_CHUNK;
  const int NB    = (N + BROWS - 1) >> BSHIFT;  // 293
  const size_t esbytes = (size_t)N * DIMS * 2;  // bf16 embeddings
  const size_t tbytes  = (size_t)NB * BCAP * 4;
  const size_t xbytes  = tbytes > esbytes ? tbytes : esbytes;

  // pass_a grid: each block covers PA_CHUNK first-half edge-pairs (mirrored)
  const int half  = nnz >> 1;
  const int PA_B  = (half + PA_CHUNK - 1) / PA_CHUNK;

  char*  ws  = (char*)d_ws;
  size_t off = 0;
  auto take = [&](size_t bytes) -> void* {
    void* p = ws + off;
    off = (off + bytes + 255) & ~(size_t)255;
    return p;
  };
  int*     cnt        = (int*)take((size_t)N * 4);
  float*   rs         = (float*)take((size_t)N * 4);
  float*   rs2        = (float*)take((size_t)N * 4);
  float*   irs        = (float*)take((size_t)N * 4);
  int*     row_ptr    = (int*)take((size_t)(N + 1) * 4);
  int*     block_sums = (int*)take((size_t)256 * 4);
  int*     gcur       = (int*)take((size_t)NB * 4);
  int*     csr_col    = (int*)take((size_t)nnz * 4);
  char*    X          = (char*)take(xbytes);   // temp (build), then bufA (Es)
  unsigned short* bufB = (unsigned short*)take(esbytes);
  float*   accU       = (float*)take((size_t)batch * DIMS * 4);
  float*   accI       = (float*)take((size_t)batch * DIMS * 4);
  unsigned* temp      = (unsigned*)X;
  unsigned short* bufA = (unsigned short*)X;

  // ---- CSR build (uses X as temp) ----
  bucket_init_kernel<<<(NB + 255) / 256, 256, 0, stream>>>(gcur, NB);
  pass_a_kernel<<<PA_B, PA_THREADS, 0, stream>>>(arows, acols, temp, gcur, nnz, NB);
  hist_bucket_kernel<<<NB, 512, 0, stream>>>(temp, gcur, cnt, N);
  scan_phase1<<<n_scan_blocks, 256, 0, stream>>>(cnt, block_sums, N);
  scan_phase2<<<1, 256, 0, stream>>>(block_sums, n_scan_blocks, row_ptr, N);
  scan_phase3<<<n_scan_blocks, 256, 0, stream>>>(cnt, block_sums, row_ptr, N);
  rs_kernel<<<(N + 255) / 256, 256, 0, stream>>>(cnt, rs, rs2, irs, N);
  pass_b_kernel<<<NB, PB_THREADS, 0, stream>>>(temp, gcur, row_ptr,
                                               csr_col, NB, N);

  // ---- batch acc init with exact fp32 E0 rows (no memset needed) ----
  gather0_kernel<<<(batch + 3) / 4, 256, 0, stream>>>(u, it, U, V, accU, accI,
                                                      batch);

  // ---- Es0 = rs * E0 in bf16 (X becomes bufA now that temp is dead) ----
  {
    int total = N * DIMS;
    int t4 = total / 4;
    init_es_kernel<<<(t4 + 255) / 256, 256, 0, stream>>>(U, V, rs, bufA,
                                                         nU * DIMS, total);
  }

  // ---- layers 1,2: full SpMM + batch gather; layer 3: batch-restricted ----
  unsigned short* cur = bufA;
  unsigned short* nxt = bufB;
  for (int layer = 0; layer < 2; ++layer) {
    spmm_kernel<<<(N + 3) / 4, 256, 0, stream>>>(
        row_ptr, csr_col, rs2, (const uint2*)cur, (uint2*)nxt, N);
    gather_s_kernel<<<(batch + 3) / 4, 256, 0, stream>>>(u, it, nxt, irs, accU,
                                                         accI, batch, nU);
    unsigned short* t = cur; cur = nxt; nxt = t;
  }
  batch_spmm_kernel<<<(2 * batch + 3) / 4, 256, 0, stream>>>(
      u, it, row_ptr, csr_col, rs, (const uint2*)cur, accU, accI, batch, nU);

  score_kernel<<<(batch + 3) / 4, 256, 0, stream>>>(accU, accI, (float*)d_out, batch);
}

// Round 6
// 834.330 us; speedup vs baseline: 2.1482x; 1.0278x over previous
//
#include <hip/hip_runtime.h>

#define DIMS 64
#define SCAN_CHUNK 2048  // 256 threads * 8 elems
#define BSHIFT 10        // 1024 rows per bucket
#define BROWS (1 << BSHIFT)
#define NB_MAX 304       // >= ceil(300K/1024)=293
#define BCAP 65536       // fixed bucket capacity (mean ~34K + drain pads <54K)
#define SCAP 40          // staged entries per bucket (mirror staging doubles arrival)
#define SPITCH 41        // odd pitch -> bank-conflict-free across buckets
#define PA_THREADS 256
#define PA_K 4           // edge-PAIRS per thread per round (int4 vector loads)
#define PA_ROUND (PA_THREADS * PA_K)  // 1024 pairs -> 2048 staged entries/round
#define PA_CHUNK 4096    // edge-pairs per block (4 rounds)
#define PB_THREADS 512
#define SENTINEL 0xFFFFFFFFu

// nt 4B load (edge col stream): keep the 40MB/layer CSR stream from
// polluting L2, which stays dedicated to the hot 38MB bf16 gather target
__device__ __forceinline__ int ld_nt_int(const int* p) {
  return __builtin_nontemporal_load(p);
}

// bf16 <-> f32 helpers (storage-only bf16; all math in fp32)
__device__ __forceinline__ float bf_lo(unsigned u) {
  return __uint_as_float(u << 16);
}
__device__ __forceinline__ float bf_hi(unsigned u) {
  return __uint_as_float(u & 0xFFFF0000u);
}
__device__ __forceinline__ unsigned f2bf(float f) {  // RNE round to bf16
  unsigned u = __float_as_uint(f);
  return (u + 0x7FFFu + ((u >> 16) & 1u)) >> 16;
}

// ---------------------------------------------------------------------------
// Es0 = rs * concat(U,V) stored bf16 (pre-scaled S-space embeddings)
// ---------------------------------------------------------------------------
__global__ __launch_bounds__(256) void init_es_kernel(
    const float* __restrict__ U, const float* __restrict__ V,
    const float* __restrict__ rs, unsigned short* __restrict__ Es,
    int nU_elems, int total_elems) {
  int i4 = (blockIdx.x * blockDim.x + threadIdx.x) * 4;
  if (i4 >= total_elems) return;
  float4 v = (i4 < nU_elems)
      ? *reinterpret_cast<const float4*>(U + i4)
      : *reinterpret_cast<const float4*>(V + (i4 - nU_elems));
  float s = rs[i4 >> 6];
  uint2 o;
  o.x = f2bf(v.x * s) | (f2bf(v.y * s) << 16);
  o.y = f2bf(v.z * s) | (f2bf(v.w * s) << 16);
  *reinterpret_cast<uint2*>(Es + i4) = o;
}

// ---------------------------------------------------------------------------
// Pass A: LDS-staged multisplit of packed (row_low<<19 | col) 4B entries into
// fixed-capacity row-range buckets (base = b*BCAP).
// Mirror staging: the symmetric COO's second half is exactly the mirror of
// the first (rows=concat[uu,ii], cols=concat[ii,uu]), so each thread loads
// only first-half (u,i) pairs and stages BOTH orientations -- same staged
// multiset, half the rounds, half the load-latency exposure.
// Flush quantum = 16 entries = one full 64B line at an aligned offset;
// flush fully drains (while >=16) so residue stays <16 with SCAP=40.
// ---------------------------------------------------------------------------
__global__ __launch_bounds__(PA_THREADS) void pass_a_kernel(
    const int* __restrict__ rows, const int* __restrict__ cols,
    unsigned* __restrict__ temp, int* __restrict__ gcur, int nnz, int nb) {
  __shared__ unsigned stage[NB_MAX * SPITCH];
  __shared__ int scnt[NB_MAX];
  for (int b = threadIdx.x; b < nb; b += PA_THREADS) scnt[b] = 0;
  __syncthreads();

  const int half = nnz >> 1;
  const int c0 = blockIdx.x * PA_CHUNK;
  const int c1 = min(half, c0 + PA_CHUNK);

  for (int rd = 0; rd < PA_CHUNK / PA_ROUND; ++rd) {
    int base = c0 + rd * PA_ROUND + threadIdx.x * PA_K;

    unsigned packed[2 * PA_K];
    int bkt[2 * PA_K];
    unsigned pend = 0;  // bitmask of entries not yet staged
    if (base + PA_K <= c1) {  // base is always 16B-aligned by construction
      int4 r4 = *reinterpret_cast<const int4*>(rows + base);
      int4 c4 = *reinterpret_cast<const int4*>(cols + base);
      int rr[PA_K] = {r4.x, r4.y, r4.z, r4.w};
      int cc[PA_K] = {c4.x, c4.y, c4.z, c4.w};
#pragma unroll
      for (int k = 0; k < PA_K; ++k) {
        bkt[2 * k] = rr[k] >> BSHIFT;
        packed[2 * k] =
            ((unsigned)(rr[k] & (BROWS - 1)) << 19) | (unsigned)cc[k];
        bkt[2 * k + 1] = cc[k] >> BSHIFT;
        packed[2 * k + 1] =
            ((unsigned)(cc[k] & (BROWS - 1)) << 19) | (unsigned)rr[k];
      }
      pend = (1u << (2 * PA_K)) - 1;
    } else {
#pragma unroll
      for (int k = 0; k < PA_K; ++k) {
        int e = base + k;
        if (e < c1) {
          int r = rows[e];
          int c = cols[e];
          bkt[2 * k] = r >> BSHIFT;
          packed[2 * k] = ((unsigned)(r & (BROWS - 1)) << 19) | (unsigned)c;
          bkt[2 * k + 1] = c >> BSHIFT;
          packed[2 * k + 1] = ((unsigned)(c & (BROWS - 1)) << 19) | (unsigned)r;
          pend |= 3u << (2 * k);
        }
      }
    }

    for (;;) {
#pragma unroll
      for (int k = 0; k < 2 * PA_K; ++k) {
        if (pend & (1u << k)) {
          int idx = atomicAdd(&scnt[bkt[k]], 1);
          if (idx < SCAP) {
            stage[bkt[k] * SPITCH + idx] = packed[k];
            pend &= ~(1u << k);
          } else {
            atomicAdd(&scnt[bkt[k]], -1);  // undo failed claim; retry after flush
          }
        }
      }
      __syncthreads();
      // flush ALL full 16-groups (one thread per bucket, conflict-free pitch)
      for (int bb = threadIdx.x; bb < nb; bb += PA_THREADS) {
        int cval = scnt[bb];
        if (cval >= 16) {
          while (cval >= 16) {
            int pos = atomicAdd(&gcur[bb], 16);
            unsigned v[16];
#pragma unroll
            for (int k = 0; k < 16; ++k) v[k] = stage[bb * SPITCH + k];
            uint4* dst = reinterpret_cast<uint4*>(&temp[pos]);
            dst[0] = make_uint4(v[0], v[1], v[2], v[3]);
            dst[1] = make_uint4(v[4], v[5], v[6], v[7]);
            dst[2] = make_uint4(v[8], v[9], v[10], v[11]);
            dst[3] = make_uint4(v[12], v[13], v[14], v[15]);
            for (int k = 0; k < cval - 16; ++k)
              stage[bb * SPITCH + k] = stage[bb * SPITCH + 16 + k];
            cval -= 16;
          }
          scnt[bb] = cval;
        }
      }
      int pend_total = __syncthreads_count(pend ? 1 : 0);
      if (pend_total == 0) break;
    }
  }
  // final drain: pad residue to a full aligned 16-group with sentinels
  __syncthreads();
  for (int bb = threadIdx.x; bb < nb; bb += PA_THREADS) {
    int cval = scnt[bb];
    if (cval > 0) {
      int pos = atomicAdd(&gcur[bb], 16);
      for (int k = 0; k < 16; ++k)
        temp[pos + k] = (k < cval) ? stage[bb * SPITCH + k] : SENTINEL;
    }
  }
}

// ---------------------------------------------------------------------------
// Per-bucket histogram: LDS atomics + coalesced contiguous cnt stores.
// ---------------------------------------------------------------------------
__global__ __launch_bounds__(512) void hist_bucket_kernel(
    const unsigned* __restrict__ temp, const int* __restrict__ gcur,
    int* __restrict__ cnt, int n) {
  __shared__ int lcnt[BROWS];
  int b = blockIdx.x;
  int base_row = b << BSHIFT;
  int nrows = min(BROWS, n - base_row);
  for (int r = threadIdx.x; r < BROWS; r += 512) lcnt[r] = 0;
  __syncthreads();
  int start = b * BCAP, end = gcur[b];
  for (int i = start + threadIdx.x; i < end; i += 512) {
    unsigned ent = temp[i];
    if (ent != SENTINEL) atomicAdd(&lcnt[ent >> 19], 1);
  }
  __syncthreads();
  for (int r = threadIdx.x; r < nrows; r += 512)
    cnt[base_row + r] = lcnt[r];
}

// phase1: per-block chunk reduction
__global__ __launch_bounds__(256) void scan_phase1(
    const int* __restrict__ cnt, int* __restrict__ block_sums, int n) {
  __shared__ int sdata[256];
  int base = blockIdx.x * SCAN_CHUNK;
  int sum = 0;
#pragma unroll
  for (int k = 0; k < 8; ++k) {
    int idx = base + k * 256 + threadIdx.x;
    if (idx < n) sum += cnt[idx];
  }
  sdata[threadIdx.x] = sum;
  __syncthreads();
  for (int s = 128; s > 0; s >>= 1) {
    if (threadIdx.x < s) sdata[threadIdx.x] += sdata[threadIdx.x + s];
    __syncthreads();
  }
  if (threadIdx.x == 0) block_sums[blockIdx.x] = sdata[0];
}

// phase2: single 256-wide exclusive scan over block sums; writes row_ptr[n]
__global__ __launch_bounds__(256) void scan_phase2(
    int* __restrict__ block_sums, int n_blocks, int* __restrict__ row_ptr, int n) {
  __shared__ int tmp[256];
  int v = (threadIdx.x < n_blocks) ? block_sums[threadIdx.x] : 0;
  tmp[threadIdx.x] = v;
  __syncthreads();
  for (int offs = 1; offs < 256; offs <<= 1) {
    int t = (threadIdx.x >= offs) ? tmp[threadIdx.x - offs] : 0;
    __syncthreads();
    tmp[threadIdx.x] += t;
    __syncthreads();
  }
  if (threadIdx.x < n_blocks) block_sums[threadIdx.x] = tmp[threadIdx.x] - v;
  if (threadIdx.x == 0) row_ptr[n] = tmp[255];
}

// phase3: per-block chunk scan with offset, writes row_ptr
__global__ __launch_bounds__(256) void scan_phase3(
    const int* __restrict__ cnt, const int* __restrict__ block_sums,
    int* __restrict__ row_ptr, int n) {
  __shared__ int tmp[256];
  __shared__ int s_carry;
  int base = blockIdx.x * SCAN_CHUNK;
  if (threadIdx.x == 0) s_carry = block_sums[blockIdx.x];
  __syncthreads();
#pragma unroll 1
  for (int k = 0; k < 8; ++k) {
    int idx = base + k * 256 + threadIdx.x;
    int v = (idx < n) ? cnt[idx] : 0;
    tmp[threadIdx.x] = v;
    __syncthreads();
    for (int offs = 1; offs < 256; offs <<= 1) {
      int t = (threadIdx.x >= offs) ? tmp[threadIdx.x - offs] : 0;
      __syncthreads();
      tmp[threadIdx.x] += t;
      __syncthreads();
    }
    int incl = tmp[threadIdx.x];
    int carry = s_carry;
    if (idx < n) row_ptr[idx] = carry + incl - v;
    __syncthreads();
    if (threadIdx.x == 0) s_carry = carry + tmp[255];
    __syncthreads();
  }
}

// rs = 1/sqrt(deg); rs2 = rs*rs (output scale); irs = sqrt(deg) (unscale)
__global__ __launch_bounds__(256) void rs_kernel(
    const int* __restrict__ cnt, float* __restrict__ rs,
    float* __restrict__ rs2, float* __restrict__ irs, int n) {
  int i = blockIdx.x * blockDim.x + threadIdx.x;
  if (i < n) {
    float d = (float)cnt[i];
    float r = (d > 0.0f) ? 1.0f / sqrtf(d) : 1.0f;
    rs[i] = r;
    rs2[i] = r * r;
    irs[i] = (d > 0.0f) ? sqrtf(d) : 1.0f;
  }
}

// gcur init for fixed-capacity buckets
__global__ __launch_bounds__(256) void bucket_init_kernel(
    int* __restrict__ gcur, int nb) {
  int b = blockIdx.x * blockDim.x + threadIdx.x;
  if (b < nb) gcur[b] = b * BCAP;
}

// ---------------------------------------------------------------------------
// Pass B: per bucket, scatter bucket entries to exact CSR positions.
// S-space iteration needs no per-edge value: CSR payload is just the col id.
// One bucket per block (grid = NB).
// ---------------------------------------------------------------------------
__global__ __launch_bounds__(PB_THREADS) void pass_b_kernel(
    const unsigned* __restrict__ temp, const int* __restrict__ gcur,
    const int* __restrict__ row_ptr, int* __restrict__ csr_col, int nb, int n) {
  __shared__ int ldscur[BROWS];
  for (int b = blockIdx.x; b < nb; b += gridDim.x) {
    int base_row = b << BSHIFT;
    int nrows = min(BROWS, n - base_row);
    for (int r = threadIdx.x; r < nrows; r += PB_THREADS)
      ldscur[r] = row_ptr[base_row + r];
    __syncthreads();
    int start = b * BCAP, end = gcur[b];
    for (int i = start + threadIdx.x; i < end; i += PB_THREADS) {
      unsigned ent = temp[i];
      if (ent != SENTINEL) {
        int col = (int)(ent & 0x7FFFFu);
        int rlow = (int)(ent >> 19);
        int p = atomicAdd(&ldscur[rlow], 1);
        csr_col[p] = col;
      }
    }
    __syncthreads();
  }
}

// ---------------------------------------------------------------------------
// SpMM in S-space, bf16 storage: one wave per row; 8 lanes per row x 16B
// (uint4) each -> one gather instruction moves 8 rows x 128B = 1KB, and
// per-edge address VALU is replicated over 8 lanes instead of 16.
// Main loop: 32 edges/iter, 4 x 16B gathers in flight per lane, NO masks.
// Tail: single predicated pass of up to 32 edges (clamped dup load, zeroed).
// acc in fp32; epilogue applies rs2[row], packs bf16; lanes q==0 store 128B.
// ---------------------------------------------------------------------------
__global__ __launch_bounds__(256) void spmm_kernel(
    const int* __restrict__ row_ptr, const int* __restrict__ csr_col,
    const float* __restrict__ rs2, const uint4* __restrict__ cur4,
    uint4* __restrict__ next4, int n_rows) {
  int row  = blockIdx.x * (blockDim.x >> 6) + (threadIdx.x >> 6);
  int lane = threadIdx.x & 63;
  int q    = lane >> 3;   // group: which edge of the group of 8
  int sub  = lane & 7;    // 16B chunk (8 bf16 dims) within the gathered row
  if (row >= n_rows) return;
  int start = row_ptr[row];
  int end   = row_ptr[row + 1];
  float acc[8];
#pragma unroll
  for (int d = 0; d < 8; ++d) acc[d] = 0.0f;
  int e = start;
  for (; e + 32 <= end; e += 32) {  // unmasked main loop
    int c[4];
    uint4 g[4];
#pragma unroll
    for (int k = 0; k < 4; ++k) c[k] = ld_nt_int(csr_col + e + 8 * k + q);
#pragma unroll
    for (int k = 0; k < 4; ++k) g[k] = cur4[(size_t)c[k] * 8 + sub];
#pragma unroll
    for (int k = 0; k < 4; ++k) {
      acc[0] += bf_lo(g[k].x); acc[1] += bf_hi(g[k].x);
      acc[2] += bf_lo(g[k].y); acc[3] += bf_hi(g[k].y);
      acc[4] += bf_lo(g[k].z); acc[5] += bf_hi(g[k].z);
      acc[6] += bf_lo(g[k].w); acc[7] += bf_hi(g[k].w);
    }
  }
  if (e < end) {  // single masked tail pass (1..31 edges)
    int c[4];
    bool m[4];
    uint4 g[4];
#pragma unroll
    for (int k = 0; k < 4; ++k) {
      int idx = e + 8 * k + q;
      m[k] = idx < end;
      c[k] = ld_nt_int(csr_col + (m[k] ? idx : (end - 1)));
    }
#pragma unroll
    for (int k = 0; k < 4; ++k) g[k] = cur4[(size_t)c[k] * 8 + sub];
#pragma unroll
    for (int k = 0; k < 4; ++k) {
      unsigned gx = m[k] ? g[k].x : 0u;
      unsigned gy = m[k] ? g[k].y : 0u;
      unsigned gz = m[k] ? g[k].z : 0u;
      unsigned gw = m[k] ? g[k].w : 0u;
      acc[0] += bf_lo(gx); acc[1] += bf_hi(gx);
      acc[2] += bf_lo(gy); acc[3] += bf_hi(gy);
      acc[4] += bf_lo(gz); acc[5] += bf_hi(gz);
      acc[6] += bf_lo(gw); acc[7] += bf_hi(gw);
    }
  }
  // combine the eight group partial sums (over q; sub stays fixed)
#pragma unroll
  for (int offs = 8; offs <= 32; offs <<= 1) {
#pragma unroll
    for (int d = 0; d < 8; ++d) acc[d] += __shfl_xor(acc[d], offs, 64);
  }
  if (q == 0) {
    float s = rs2[row];
    uint4 o;
    o.x = f2bf(acc[0] * s) | (f2bf(acc[1] * s) << 16);
    o.y = f2bf(acc[2] * s) | (f2bf(acc[3] * s) << 16);
    o.z = f2bf(acc[4] * s) | (f2bf(acc[5] * s) << 16);
    o.w = f2bf(acc[6] * s) | (f2bf(acc[7] * s) << 16);
    next4[(size_t)row * 8 + sub] = o;
  }
}

// ---------------------------------------------------------------------------
// Layer-3 batch-restricted SpMM: only the 2*batch rows needed by the output.
// acc[b] += rs[row] * sum_{c in N(row)} S2[c]   (== gather(E3) exactly)
// One wave per (batch-slot, side) task; predicated quarter-gather loop.
// ---------------------------------------------------------------------------
__global__ __launch_bounds__(256) void batch_spmm_kernel(
    const int* __restrict__ u, const int* __restrict__ it,
    const int* __restrict__ row_ptr, const int* __restrict__ csr_col,
    const float* __restrict__ rs, const uint2* __restrict__ cur2,
    float* __restrict__ accU, float* __restrict__ accI, int batch, int nU) {
  int t    = blockIdx.x * (blockDim.x >> 6) + (threadIdx.x >> 6);
  int lane = threadIdx.x & 63;
  int q    = lane >> 4;
  int sub  = lane & 15;
  if (t >= 2 * batch) return;
  int b = t >> 1;
  bool uside = (t & 1) == 0;
  int row = uside ? u[b] : (it[b] + nU);
  int start = row_ptr[row];
  int end   = row_ptr[row + 1];
  float4 acc = make_float4(0.0f, 0.0f, 0.0f, 0.0f);
  for (int e = start; e < end; e += 16) {
    int c[4];
    bool m[4];
    uint2 g[4];
#pragma unroll
    for (int k = 0; k < 4; ++k) {
      int idx = e + 4 * k + q;
      m[k] = idx < end;
      c[k] = ld_nt_int(csr_col + (m[k] ? idx : (end - 1)));
    }
#pragma unroll
    for (int k = 0; k < 4; ++k) g[k] = cur2[c[k] * 16 + sub];
#pragma unroll
    for (int k = 0; k < 4; ++k) {
      unsigned gx = m[k] ? g[k].x : 0u;
      unsigned gy = m[k] ? g[k].y : 0u;
      acc.x += bf_lo(gx); acc.y += bf_hi(gx);
      acc.z += bf_lo(gy); acc.w += bf_hi(gy);
    }
  }
#pragma unroll
  for (int offs = 16; offs <= 32; offs <<= 1) {
    acc.x += __shfl_xor(acc.x, offs, 64);
    acc.y += __shfl_xor(acc.y, offs, 64);
    acc.z += __shfl_xor(acc.z, offs, 64);
    acc.w += __shfl_xor(acc.w, offs, 64);
  }
  if (q == 0) {
    float s = rs[row];
    float* dst = (uside ? accU : accI) + (size_t)b * DIMS + sub * 4;
    float4 old = *reinterpret_cast<float4*>(dst);
    old.x += acc.x * s; old.y += acc.y * s;
    old.z += acc.z * s; old.w += acc.w * s;
    *reinterpret_cast<float4*>(dst) = old;
  }
}

// ---------------------------------------------------------------------------
// Layer-0 batch gather: exact fp32 E0 rows straight from U/V (initializes acc)
// ---------------------------------------------------------------------------
__global__ __launch_bounds__(256) void gather0_kernel(
    const int* __restrict__ u, const int* __restrict__ it,
    const float* __restrict__ U, const float* __restrict__ V,
    float* __restrict__ accU, float* __restrict__ accI, int batch) {
  int b    = blockIdx.x * (blockDim.x >> 6) + (threadIdx.x >> 6);
  int lane = threadIdx.x & 63;
  if (b >= batch) return;
  accU[b * DIMS + lane] = U[u[b] * DIMS + lane];
  accI[b * DIMS + lane] = V[it[b] * DIMS + lane];
}

// Layer-k batch gather from S-space bf16: unscale by irs = sqrt(deg)
__global__ __launch_bounds__(256) void gather_s_kernel(
    const int* __restrict__ u, const int* __restrict__ it,
    const unsigned short* __restrict__ curS, const float* __restrict__ irs,
    float* __restrict__ accU, float* __restrict__ accI, int batch, int nU) {
  int b    = blockIdx.x * (blockDim.x >> 6) + (threadIdx.x >> 6);
  int lane = threadIdx.x & 63;
  if (b >= batch) return;
  int ru = u[b];
  int ri = it[b] + nU;
  accU[b * DIMS + lane] +=
      __uint_as_float((unsigned)curS[ru * DIMS + lane] << 16) * irs[ru];
  accI[b * DIMS + lane] +=
      __uint_as_float((unsigned)curS[ri * DIMS + lane] << 16) * irs[ri];
}

__global__ __launch_bounds__(256) void score_kernel(
    const float* __restrict__ accU, const float* __restrict__ accI,
    float* __restrict__ out, int batch) {
  int b    = blockIdx.x * (blockDim.x >> 6) + (threadIdx.x >> 6);
  int lane = threadIdx.x & 63;
  if (b >= batch) return;
  float v = accU[b * DIMS + lane] * accI[b * DIMS + lane];
  for (int offs = 32; offs > 0; offs >>= 1) v += __shfl_down(v, offs, 64);
  if (lane == 0) out[b] = v * (1.0f / 16.0f);
}

// ---------------------------------------------------------------------------
extern "C" void kernel_launch(void* const* d_in, const int* in_sizes, int n_in,
                              void* d_out, int out_size, void* d_ws, size_t ws_size,
                              hipStream_t stream) {
  const int*   u     = (const int*)d_in[0];
  const int*   it    = (const int*)d_in[1];
  const int*   arows = (const int*)d_in[2];
  const int*   acols = (const int*)d_in[3];
  const float* U     = (const float*)d_in[5];
  const float* V     = (const float*)d_in[6];

  const int batch = in_sizes[0];
  const int nnz   = in_sizes[2];
  const int nU    = in_sizes[5] / DIMS;
  const int nV    = in_sizes[6] / DIMS;
  const int N     = nU + nV;
  const int n_scan_blocks = (N + SCAN_CHUNK - 1) / SCAN_CHUNK;
  const int NB    = (N + BROWS - 1) >> BSHIFT;  // 293
  const size_t esbytes = (size_t)N * DIMS * 2;  // bf16 embeddings
  const size_t tbytes  = (size_t)NB * BCAP * 4;
  const size_t xbytes  = tbytes > esbytes ? tbytes : esbytes;

  // pass_a grid: each block covers PA_CHUNK first-half edge-pairs (mirrored)
  const int half  = nnz >> 1;
  const int PA_B  = (half + PA_CHUNK - 1) / PA_CHUNK;

  char*  ws  = (char*)d_ws;
  size_t off = 0;
  auto take = [&](size_t bytes) -> void* {
    void* p = ws + off;
    off = (off + bytes + 255) & ~(size_t)255;
    return p;
  };
  int*     cnt        = (int*)take((size_t)N * 4);
  float*   rs         = (float*)take((size_t)N * 4);
  float*   rs2        = (float*)take((size_t)N * 4);
  float*   irs        = (float*)take((size_t)N * 4);
  int*     row_ptr    = (int*)take((size_t)(N + 1) * 4);
  int*     block_sums = (int*)take((size_t)256 * 4);
  int*     gcur       = (int*)take((size_t)NB * 4);
  int*     csr_col    = (int*)take((size_t)nnz * 4);
  char*    X          = (char*)take(xbytes);   // temp (build), then bufA (Es)
  unsigned short* bufB = (unsigned short*)take(esbytes);
  float*   accU       = (float*)take((size_t)batch * DIMS * 4);
  float*   accI       = (float*)take((size_t)batch * DIMS * 4);
  unsigned* temp      = (unsigned*)X;
  unsigned short* bufA = (unsigned short*)X;

  // ---- CSR build (uses X as temp) ----
  bucket_init_kernel<<<(NB + 255) / 256, 256, 0, stream>>>(gcur, NB);
  pass_a_kernel<<<PA_B, PA_THREADS, 0, stream>>>(arows, acols, temp, gcur, nnz, NB);
  hist_bucket_kernel<<<NB, 512, 0, stream>>>(temp, gcur, cnt, N);
  scan_phase1<<<n_scan_blocks, 256, 0, stream>>>(cnt, block_sums, N);
  scan_phase2<<<1, 256, 0, stream>>>(block_sums, n_scan_blocks, row_ptr, N);
  scan_phase3<<<n_scan_blocks, 256, 0, stream>>>(cnt, block_sums, row_ptr, N);
  rs_kernel<<<(N + 255) / 256, 256, 0, stream>>>(cnt, rs, rs2, irs, N);
  pass_b_kernel<<<NB, PB_THREADS, 0, stream>>>(temp, gcur, row_ptr,
                                               csr_col, NB, N);

  // ---- batch acc init with exact fp32 E0 rows (no memset needed) ----
  gather0_kernel<<<(batch + 3) / 4, 256, 0, stream>>>(u, it, U, V, accU, accI,
                                                      batch);

  // ---- Es0 = rs * E0 in bf16 (X becomes bufA now that temp is dead) ----
  {
    int total = N * DIMS;
    int t4 = total / 4;
    init_es_kernel<<<(t4 + 255) / 256, 256, 0, stream>>>(U, V, rs, bufA,
                                                         nU * DIMS, total);
  }

  // ---- layers 1,2: full SpMM + batch gather; layer 3: batch-restricted ----
  unsigned short* cur = bufA;
  unsigned short* nxt = bufB;
  for (int layer = 0; layer < 2; ++layer) {
    spmm_kernel<<<(N + 3) / 4, 256, 0, stream>>>(
        row_ptr, csr_col, rs2, (const uint4*)cur, (uint4*)nxt, N);
    gather_s_kernel<<<(batch + 3) / 4, 256, 0, stream>>>(u, it, nxt, irs, accU,
                                                         accI, batch, nU);
    unsigned short* t = cur; cur = nxt; nxt = t;
  }
  batch_spmm_kernel<<<(2 * batch + 3) / 4, 256, 0, stream>>>(
      u, it, row_ptr, csr_col, rs, (const uint2*)cur, accU, accI, batch, nU);

  score_kernel<<<(batch + 3) / 4, 256, 0, stream>>>(accU, accI, (float*)d_out, batch);
}